// Round 5
// baseline (1398.115 us; speedup 1.0000x reference)
//
#include <hip/hip_runtime.h>
#include <hip/hip_bf16.h>
#include <math.h>

#define N0c 120000
#define N1c 20000
#define N2c 6000
#define N3c 1600
#define Bc  64
#define E1c 480000
#define E2c 144000
#define E3c 38400

__device__ __forceinline__ float eluf(float x) {
    return x > 0.0f ? x : expm1f(x);
}

// monotone float -> uint mapping for atomicMax-based segment max
__device__ __forceinline__ unsigned f2sort(float f) {
    unsigned u = __float_as_uint(f);
    return (u & 0x80000000u) ? ~u : (u | 0x80000000u);
}
__device__ __forceinline__ float sort2f(unsigned u) {
    unsigned bits = (u & 0x80000000u) ? (u & 0x7FFFFFFFu) : ~u;
    return __uint_as_float(bits);
}

__global__ void segmax_scatter(const float* __restrict__ x, const int* __restrict__ cl,
                               unsigned* __restrict__ buf, int total, int shiftC) {
    int idx = blockIdx.x * blockDim.x + threadIdx.x;
    if (idx >= total) return;
    int n = idx >> shiftC;
    int c = idx - (n << shiftC);
    atomicMax(&buf[(cl[n] << shiftC) + c], f2sort(x[idx]));
}

__global__ void segmax_decode(unsigned* __restrict__ buf, int total) {
    int idx = blockIdx.x * blockDim.x + threadIdx.x;
    if (idx >= total) return;
    float f = sort2f(buf[idx]);
    unsigned b = __float_as_uint(f);
    if ((b & 0x7F800000u) == 0x7F800000u) f = 0.0f;   // !isfinite -> 0
    ((float*)buf)[idx] = f;
}

// ---- generic CSR-by-dst-key helpers (key = dst >> shift) ----

__global__ void key_hist(const int* __restrict__ edge, int E, int shift,
                         int* __restrict__ cnt) {
    int e = blockIdx.x * blockDim.x + threadIdx.x;
    if (e >= E) return;
    atomicAdd(&cnt[edge[E + e] >> shift], 1);
}

// single-block exclusive scan, n up to ~6k
__global__ void scan_excl(const int* __restrict__ cnt, int* __restrict__ start, int n) {
    __shared__ int buf[256];
    __shared__ int carryS;
    int t = threadIdx.x;
    if (t == 0) carryS = 0;
    __syncthreads();
    for (int base = 0; base < n; base += 256) {
        int i = base + t;
        int v = (i < n) ? cnt[i] : 0;
        buf[t] = v;
        __syncthreads();
        for (int ofs = 1; ofs < 256; ofs <<= 1) {
            int add = (t >= ofs) ? buf[t - ofs] : 0;
            __syncthreads();
            buf[t] += add;
            __syncthreads();
        }
        if (i < n) start[i] = carryS + buf[t] - v;
        __syncthreads();
        if (t == 0) carryS += buf[255];
        __syncthreads();
    }
    if (t == 0) start[n] = carryS;
}

__global__ void key_scatter(const int* __restrict__ edge, int E, int shift,
                            const int* __restrict__ start, int* __restrict__ cursor,
                            int* __restrict__ ord) {
    int e = blockIdx.x * blockDim.x + threadIdx.x;
    if (e >= E) return;
    int d = edge[E + e] >> shift;
    int p = atomicAdd(&cursor[d], 1);
    ord[start[d] + p] = e;
}

// ---- conv1 (C_in=1): per-16-node block, LDS knot accumulation + tiny GEMM ----
// Block b owns nodes [16b, 16b+16). Edges pre-sorted by dst>>4.
// T[ln][k] accumulated with LDS atomics; then out = elu(T@W1/deg + x*root + b).
__global__ __launch_bounds__(256) void conv1_block(
    const int* __restrict__ edge, const float* __restrict__ pseudo,
    const float* __restrict__ x,
    const int* __restrict__ start, const int* __restrict__ order,
    const float* __restrict__ W, const float* __restrict__ root,
    const float* __restrict__ bias, float* __restrict__ out) {
    __shared__ float T[16][128];
    __shared__ int degL[16];
    int b = blockIdx.x;
    for (int j = threadIdx.x; j < 2048; j += 256) ((float*)T)[j] = 0.0f;
    if (threadIdx.x < 16) degL[threadIdx.x] = 0;
    __syncthreads();
    int s0 = start[b], s1 = start[b + 1];
    for (int i = s0 + threadIdx.x; i < s1; i += 256) {
        int e = order[i];
        int src = edge[e], dst = edge[E1c + e];
        int ln = dst & 15;
        float xv = x[src];
        float f[3];
        int loi[3];
        #pragma unroll
        for (int d = 0; d < 3; d++) {
            float pp = pseudo[e * 3 + d] * 4.0f;
            float l = fminf(fmaxf(floorf(pp), 0.0f), 3.0f);
            f[d] = pp - l;
            loi[d] = (int)l;
        }
        int kbase = loi[0] + 5 * loi[1] + 25 * loi[2];
        #pragma unroll
        for (int s = 0; s < 8; s++) {
            int b0 = s & 1, b1 = (s >> 1) & 1, b2 = (s >> 2) & 1;
            float w0 = b0 ? f[0] : 1.0f - f[0];
            float w1 = b1 ? f[1] : 1.0f - f[1];
            float w2 = b2 ? f[2] : 1.0f - f[2];
            int k = kbase + b0 + 5 * b1 + 25 * b2;
            atomicAdd(&T[ln][k], xv * w0 * w1 * w2);
        }
        atomicAdd(&degL[ln], 1);
    }
    __syncthreads();
    int w = threadIdx.x >> 6, lane = threadIdx.x & 63;
    float acc[4] = {0.0f, 0.0f, 0.0f, 0.0f};
    for (int k = 0; k < 125; k++) {
        float wv = W[(k << 6) + lane];
        #pragma unroll
        for (int j = 0; j < 4; j++)
            acc[j] = fmaf(T[w + 4 * j][k], wv, acc[j]);
    }
    int v0 = b << 4;
    #pragma unroll
    for (int j = 0; j < 4; j++) {
        int ln = w + 4 * j;
        int v = v0 + ln;
        float d = fmaxf((float)degL[ln], 1.0f);
        out[((size_t)v << 6) + lane] = eluf(acc[j] / d + x[v] * root[lane] + bias[lane]);
    }
}

// ---- binned spline conv (conv2/conv3): counting sort by spline cube ----

// fused: cube histogram + dst-degree histogram
__global__ void bin_hist(const int* __restrict__ edge, int E,
                         const float* __restrict__ pseudo,
                         int* __restrict__ cube, int* __restrict__ binCnt,
                         int* __restrict__ dstCnt) {
    int e = blockIdx.x * blockDim.x + threadIdx.x;
    if (e >= E) return;
    int c = 0, mul = 1;
    #pragma unroll
    for (int d = 0; d < 3; d++) {
        float p = pseudo[e * 3 + d] * 4.0f;
        float l = fminf(fmaxf(floorf(p), 0.0f), 3.0f);
        c += (int)l * mul;
        mul <<= 2;
    }
    cube[e] = c;
    atomicAdd(&binCnt[c], 1);
    atomicAdd(&dstCnt[edge[E + e]], 1);
}

// 64 threads; LDS-based scan
__global__ void bin_plan(const int* __restrict__ binCnt, int* __restrict__ binStart,
                         int* __restrict__ blkPrefix, int* __restrict__ chunkBin,
                         int* __restrict__ chunkOff) {
    __shared__ int cs[64], ss[64], ps[64];
    int t = threadIdx.x;
    cs[t] = binCnt[t];
    __syncthreads();
    if (t == 0) {
        int s = 0, p = 0;
        for (int c = 0; c < 64; c++) {
            ss[c] = s; ps[c] = p;
            s += cs[c];
            p += (cs[c] + 255) >> 8;
        }
        blkPrefix[64] = p;
    }
    __syncthreads();
    binStart[t] = ss[t];
    blkPrefix[t] = ps[t];
    int nch = (cs[t] + 255) >> 8;
    for (int j = 0; j < nch; j++) {
        chunkBin[ps[t] + j] = t;
        chunkOff[ps[t] + j] = j;
    }
}

__global__ void bin_scatter(const int* __restrict__ cube, int E,
                            const int* __restrict__ binStart, int* __restrict__ cursor,
                            int* __restrict__ order) {
    int e = blockIdx.x * blockDim.x + threadIdx.x;
    if (e >= E) return;
    int c = cube[e];
    int p = atomicAdd(&cursor[c], 1);
    order[binStart[c] + p] = e;
}

// Binned spline-conv GEMM v3: per-edge messages, NO atomics.
//  - ic (K-chunk of 16 in-channels) OUTER, tap s INNER; x staged in LDS once/ic.
//  - basis applied at FMA time from per-wave LDS table.
//  - epilogue: transpose acc through LDS, store msg[e][COUT] coalesced.
// Block = 256 thr = 4 waves; wave = 64 edges x 64 out-ch, 8x8 per thread.
template<int COUT>
__global__ __launch_bounds__(256) void spline_gemm(
    const int* __restrict__ edge, int E,
    const float* __restrict__ pseudo,
    const float* __restrict__ W,
    const float* __restrict__ x,
    const int* __restrict__ order,
    const int* __restrict__ binStart,
    const int* __restrict__ binCnt,
    const int* __restrict__ blkPrefix,
    const int* __restrict__ chunkBin,
    const int* __restrict__ chunkOff,
    float* __restrict__ msg)
{
    __shared__ float Bs[16][64];
    __shared__ float Xs[4][16][64];
    __shared__ float bsS[4][64][8];
    __shared__ int eS[4][64];

    int b = blockIdx.x;
    if (b >= blkPrefix[64]) return;
    int c = chunkBin[b];
    int chunk = chunkOff[b];
    int cnt = binCnt[c];

    int w = threadIdx.x >> 6, lane = threadIdx.x & 63;
    int pos = chunk * 256 + w * 64 + lane;
    bool active = pos < cnt;
    int e = active ? order[binStart[c] + pos] : 0;

    int src = 0;
    float f0 = 0.0f, f1 = 0.0f, f2 = 0.0f;
    if (active) {
        src = edge[e];
        float p0 = pseudo[e * 3 + 0] * 4.0f;
        float p1 = pseudo[e * 3 + 1] * 4.0f;
        float p2 = pseudo[e * 3 + 2] * 4.0f;
        f0 = p0 - fminf(fmaxf(floorf(p0), 0.0f), 3.0f);
        f1 = p1 - fminf(fmaxf(floorf(p1), 0.0f), 3.0f);
        f2 = p2 - fminf(fmaxf(floorf(p2), 0.0f), 3.0f);
    }
    eS[w][lane] = e;
    #pragma unroll
    for (int t = 0; t < 8; t++) {
        float w0 = (t & 1) ? f0 : 1.0f - f0;
        float w1 = (t & 2) ? f1 : 1.0f - f1;
        float w2 = (t & 4) ? f2 : 1.0f - f2;
        bsS[w][lane][t] = active ? (w0 * w1 * w2) : 0.0f;
    }

    int lo0 = c & 3, lo1 = (c >> 2) & 3, lo2 = c >> 4;
    int kbase = lo0 + 5 * lo1 + 25 * lo2;
    int colOff = (COUT == 128) ? (blockIdx.y << 6) : 0;
    int tm = lane >> 3, tn = lane & 7;

    float acc[8][8];
    #pragma unroll
    for (int ii = 0; ii < 8; ii++)
        #pragma unroll
        for (int jj = 0; jj < 8; jj++) acc[ii][jj] = 0.0f;

    const float* xrow = x + ((size_t)src << 6);

    #pragma unroll 1
    for (int ic = 0; ic < 64; ic += 16) {
        __syncthreads();   // prev round's Bs & Xs fully consumed
        #pragma unroll
        for (int r = 0; r < 16; r += 4) {
            float4 xq = *(const float4*)(xrow + ic + r);
            Xs[w][r + 0][lane] = xq.x;
            Xs[w][r + 1][lane] = xq.y;
            Xs[w][r + 2][lane] = xq.z;
            Xs[w][r + 3][lane] = xq.w;
        }
        #pragma unroll 1
        for (int t = 0; t < 8; t++) {
            int k = kbase + (t & 1) + 5 * ((t >> 1) & 1) + 25 * (t >> 2);
            const float* Wk = W + (size_t)k * 64 * COUT + colOff;
            if (t > 0) __syncthreads();   // Bs consumed by all waves
            #pragma unroll
            for (int r = w; r < 16; r += 4)
                Bs[r][lane] = Wk[(size_t)(ic + r) * COUT + lane];
            __syncthreads();
            float bsf[8];
            #pragma unroll
            for (int ii = 0; ii < 8; ii++) bsf[ii] = bsS[w][tm * 8 + ii][t];
            #pragma unroll
            for (int r = 0; r < 16; r++) {
                float4 a0 = *(const float4*)(&Xs[w][r][tm * 8]);
                float4 a1 = *(const float4*)(&Xs[w][r][tm * 8 + 4]);
                float4 b0 = *(const float4*)(&Bs[r][tn * 8]);
                float4 b1 = *(const float4*)(&Bs[r][tn * 8 + 4]);
                float av[8] = {a0.x * bsf[0], a0.y * bsf[1], a0.z * bsf[2], a0.w * bsf[3],
                               a1.x * bsf[4], a1.y * bsf[5], a1.z * bsf[6], a1.w * bsf[7]};
                float bv[8] = {b0.x, b0.y, b0.z, b0.w, b1.x, b1.y, b1.z, b1.w};
                #pragma unroll
                for (int ii = 0; ii < 8; ii++)
                    #pragma unroll
                    for (int jj = 0; jj < 8; jj++)
                        acc[ii][jj] = fmaf(av[ii], bv[jj], acc[ii][jj]);
            }
        }
    }

    // Epilogue: wave-private transpose through Xs[w], then coalesced stores
    // to msg[e][colOff+lane]. No atomics.
    #pragma unroll 1
    for (int pass = 0; pass < 4; pass++) {
        if ((tm >> 1) == pass) {
            int rl = (tm & 1) * 8;
            #pragma unroll
            for (int ii = 0; ii < 8; ii++) {
                *(float4*)(&Xs[w][rl + ii][tn * 8]) =
                    make_float4(acc[ii][0], acc[ii][1], acc[ii][2], acc[ii][3]);
                *(float4*)(&Xs[w][rl + ii][tn * 8 + 4]) =
                    make_float4(acc[ii][4], acc[ii][5], acc[ii][6], acc[ii][7]);
            }
        }
        __builtin_amdgcn_wave_barrier();
        int rowBase = chunk * 256 + w * 64 + pass * 16;
        #pragma unroll 1
        for (int r = 0; r < 16; r++) {
            if (rowBase + r < cnt) {
                msg[(size_t)eS[w][pass * 16 + r] * COUT + colOff + lane] = Xs[w][r][lane];
            }
        }
        __builtin_amdgcn_wave_barrier();
    }
}

// dst-CSR gather + fused node update, COUT=64. One wave per node.
__global__ __launch_bounds__(256) void conv_gather64(
    const float* __restrict__ msg, const int* __restrict__ start,
    const int* __restrict__ eidx, const float* __restrict__ xm,
    const float* __restrict__ root, const float* __restrict__ bias,
    float* __restrict__ out, int nNodes) {
    __shared__ float xsh[4][64];
    int w = threadIdx.x >> 6, lane = threadIdx.x & 63;
    int v = blockIdx.x * 4 + w;
    if (v >= nNodes) return;
    xsh[w][lane] = xm[((size_t)v << 6) + lane];
    int s0 = start[v], s1 = start[v + 1];
    float acc = 0.0f;
    int p = s0;
    for (; p + 1 < s1; p += 2) {
        int e0 = eidx[p], e1 = eidx[p + 1];
        acc += msg[((size_t)e0 << 6) + lane] + msg[((size_t)e1 << 6) + lane];
    }
    if (p < s1) acc += msg[((size_t)eidx[p] << 6) + lane];
    acc /= fmaxf((float)(s1 - s0), 1.0f);
    float r = 0.0f;
    #pragma unroll 8
    for (int i = 0; i < 64; i++)
        r = fmaf(xsh[w][i], root[(i << 6) + lane], r);
    out[((size_t)v << 6) + lane] = eluf(acc + r + bias[lane]);
}

// dst-CSR gather + fused node update, COUT=128. One wave per node (2 ch/lane).
__global__ __launch_bounds__(256) void conv_gather128(
    const float* __restrict__ msg, const int* __restrict__ start,
    const int* __restrict__ eidx, const float* __restrict__ xm,
    const float* __restrict__ root, const float* __restrict__ bias,
    float* __restrict__ out, int nNodes) {
    __shared__ float xsh[4][64];
    int w = threadIdx.x >> 6, lane = threadIdx.x & 63;
    int v = blockIdx.x * 4 + w;
    if (v >= nNodes) return;
    xsh[w][lane] = xm[((size_t)v << 6) + lane];
    int s0 = start[v], s1 = start[v + 1];
    float acc0 = 0.0f, acc1 = 0.0f;
    for (int p = s0; p < s1; p++) {
        const float* mrow = msg + ((size_t)eidx[p] << 7);
        acc0 += mrow[lane];
        acc1 += mrow[lane + 64];
    }
    float dinv = 1.0f / fmaxf((float)(s1 - s0), 1.0f);
    acc0 *= dinv; acc1 *= dinv;
    float r0 = 0.0f, r1 = 0.0f;
    #pragma unroll 8
    for (int i = 0; i < 64; i++) {
        float xi = xsh[w][i];
        r0 = fmaf(xi, root[(i << 7) + lane], r0);
        r1 = fmaf(xi, root[(i << 7) + 64 + lane], r1);
    }
    out[((size_t)v << 7) + lane] = eluf(acc0 + r0 + bias[lane]);
    out[((size_t)v << 7) + 64 + lane] = eluf(acc1 + r1 + bias[lane + 64]);
}

__global__ void fc1_k(const float* __restrict__ xin, const float* __restrict__ w,
                      const float* __restrict__ b, float* __restrict__ h) {
    __shared__ float xsh[1024];
    int row = blockIdx.x;
    for (int i = threadIdx.x; i < 1024; i += 256) xsh[i] = xin[row * 1024 + i];
    __syncthreads();
    int o = threadIdx.x;
    float acc = b[o];
    #pragma unroll 8
    for (int i = 0; i < 1024; i++) acc = fmaf(xsh[i], w[i * 256 + o], acc);
    h[row * 256 + o] = eluf(acc);
}

__global__ void fc2_k(const float* __restrict__ h, const float* __restrict__ w,
                      const float* __restrict__ b, float* __restrict__ out) {
    __shared__ float hs[256];
    __shared__ float lg[10];
    int row = blockIdx.x;
    int t = threadIdx.x;
    for (int i = t; i < 256; i += 64) hs[i] = h[row * 256 + i];
    __syncthreads();
    if (t < 10) {
        float acc = b[t];
        for (int i = 0; i < 256; i++) acc = fmaf(hs[i], w[i * 10 + t], acc);
        lg[t] = acc;
    }
    __syncthreads();
    if (t < 10) {
        float m = -1e30f;
        #pragma unroll
        for (int j = 0; j < 10; j++) m = fmaxf(m, lg[j]);
        float sum = 0.0f;
        #pragma unroll
        for (int j = 0; j < 10; j++) sum += expf(lg[j] - m);
        out[row * 10 + t] = lg[t] - m - logf(sum);
    }
}

extern "C" void kernel_launch(void* const* d_in, const int* in_sizes, int n_in,
                              void* d_out, int out_size, void* d_ws, size_t ws_size,
                              hipStream_t stream) {
    const float* x0      = (const float*)d_in[0];
    const int*   cluster0= (const int*)d_in[1];
    const int*   edge1   = (const int*)d_in[2];
    const float* pseudo1 = (const float*)d_in[3];
    const float* W1      = (const float*)d_in[4];
    const float* root1   = (const float*)d_in[5];
    const float* b1      = (const float*)d_in[6];
    const int*   cluster1= (const int*)d_in[7];
    const int*   edge2   = (const int*)d_in[8];
    const float* pseudo2 = (const float*)d_in[9];
    const float* W2      = (const float*)d_in[10];
    const float* root2   = (const float*)d_in[11];
    const float* b2      = (const float*)d_in[12];
    const int*   cluster2= (const int*)d_in[13];
    const int*   edge3   = (const int*)d_in[14];
    const float* pseudo3 = (const float*)d_in[15];
    const float* W3      = (const float*)d_in[16];
    const float* root3   = (const float*)d_in[17];
    const float* b3      = (const float*)d_in[18];
    const int*   cluster3= (const int*)d_in[19];
    const float* fc1_w   = (const float*)d_in[20];
    const float* fc1_b   = (const float*)d_in[21];
    const float* fc2_w   = (const float*)d_in[22];
    const float* fc2_b   = (const float*)d_in[23];
    float* out = (float*)d_out;

    float* ws = (float*)d_ws;
    size_t off = 0;
    // ---- zeroed region ----
    float* xm1  = ws + off; off += 20480;
    float* xm2  = ws + off; off += (size_t)N2c * 64;
    float* xm3  = ws + off; off += (size_t)N3c * 64;
    float* xm4  = ws + off; off += 512 * 128;
    int* binCnt2 = (int*)(ws + off); off += 64;
    int* cursor2 = (int*)(ws + off); off += 64;
    int* binCnt3 = (int*)(ws + off); off += 64;
    int* cursor3 = (int*)(ws + off); off += 64;
    int* cnt1    = (int*)(ws + off); off += 1280;
    int* cursor1 = (int*)(ws + off); off += 1280;
    int* cntD2   = (int*)(ws + off); off += 6016;
    int* curD2   = (int*)(ws + off); off += 6016;
    int* cntD3   = (int*)(ws + off); off += 1664;
    int* curD3   = (int*)(ws + off); off += 1664;
    size_t zeroFloats = off;
    // ---- non-zeroed region (fully written before read every launch) ----
    float* x1   = ws + off; off += (size_t)N1c * 64;
    float* x2   = ws + off; off += (size_t)N2c * 64;
    float* x3   = ws + off; off += (size_t)N3c * 128;
    float* h1   = ws + off; off += 64 * 256;
    int* cube2     = (int*)(ws + off); off += E2c;
    int* order2    = (int*)(ws + off); off += E2c;
    int* cube3     = (int*)(ws + off); off += E3c;
    int* order3    = (int*)(ws + off); off += E3c;
    int* eidx2     = (int*)(ws + off); off += E2c;
    int* start2    = (int*)(ws + off); off += 6016;
    int* eidx3     = (int*)(ws + off); off += E3c;
    int* start3    = (int*)(ws + off); off += 1664;
    int* start1    = (int*)(ws + off); off += 1280;
    int* binStart2 = (int*)(ws + off); off += 64;
    int* blkPrefix2= (int*)(ws + off); off += 80;
    int* chunkBin2 = (int*)(ws + off); off += 704;
    int* chunkOff2 = (int*)(ws + off); off += 704;
    int* binStart3 = (int*)(ws + off); off += 64;
    int* blkPrefix3= (int*)(ws + off); off += 80;
    int* chunkBin3 = (int*)(ws + off); off += 256;
    int* chunkOff3 = (int*)(ws + off); off += 256;
    // big scratch: order1 (conv1) -> msg2 (conv2) -> msg3 (conv3), serially reused
    float* big  = ws + off; off += (size_t)E2c * 64;   // 9.216M floats (largest user)
    int*   order1 = (int*)big;
    float* msg2   = big;
    float* msg3   = big;

    hipMemsetAsync(d_ws, 0, zeroFloats * sizeof(float), stream);

    // pool 0: x0 -> xm1 (N1 x 1)
    segmax_scatter<<<(N0c + 255) / 256, 256, 0, stream>>>(x0, cluster0, (unsigned*)xm1, N0c, 0);
    segmax_decode<<<(N1c + 255) / 256, 256, 0, stream>>>((unsigned*)xm1, N1c);

    // conv1 (1 -> 64): coarse sort by dst>>4, per-16-node LDS accumulation
    key_hist<<<(E1c + 255) / 256, 256, 0, stream>>>(edge1, E1c, 4, cnt1);
    scan_excl<<<1, 256, 0, stream>>>(cnt1, start1, 1250);
    key_scatter<<<(E1c + 255) / 256, 256, 0, stream>>>(edge1, E1c, 4, start1, cursor1, order1);
    conv1_block<<<1250, 256, 0, stream>>>(edge1, pseudo1, xm1, start1, order1,
                                          W1, root1, b1, x1);

    // pool 1: x1 -> xm2 (N2 x 64)
    segmax_scatter<<<(N1c * 64) / 256, 256, 0, stream>>>(x1, cluster1, (unsigned*)xm2, N1c * 64, 6);
    segmax_decode<<<(N2c * 64) / 256, 256, 0, stream>>>((unsigned*)xm2, N2c * 64);

    // conv2 (64 -> 64): cube-binned GEMM -> msg, then dst-CSR gather
    bin_hist<<<(E2c + 255) / 256, 256, 0, stream>>>(edge2, E2c, pseudo2, cube2, binCnt2, cntD2);
    bin_plan<<<1, 64, 0, stream>>>(binCnt2, binStart2, blkPrefix2, chunkBin2, chunkOff2);
    bin_scatter<<<(E2c + 255) / 256, 256, 0, stream>>>(cube2, E2c, binStart2, cursor2, order2);
    scan_excl<<<1, 256, 0, stream>>>(cntD2, start2, N2c);
    key_scatter<<<(E2c + 255) / 256, 256, 0, stream>>>(edge2, E2c, 0, start2, curD2, eidx2);
    {
        int maxBlk = (E2c + 255) / 256 + 64;
        spline_gemm<64><<<dim3(maxBlk, 1), 256, 0, stream>>>(
            edge2, E2c, pseudo2, W2, xm2, order2, binStart2, binCnt2, blkPrefix2,
            chunkBin2, chunkOff2, msg2);
    }
    conv_gather64<<<(N2c + 3) / 4, 256, 0, stream>>>(msg2, start2, eidx2, xm2,
                                                     root2, b2, x2, N2c);

    // pool 2: x2 -> xm3 (N3 x 64)
    segmax_scatter<<<(N2c * 64) / 256, 256, 0, stream>>>(x2, cluster2, (unsigned*)xm3, N2c * 64, 6);
    segmax_decode<<<(N3c * 64) / 256, 256, 0, stream>>>((unsigned*)xm3, N3c * 64);

    // conv3 (64 -> 128): cube-binned GEMM -> msg, then dst-CSR gather
    bin_hist<<<(E3c + 255) / 256, 256, 0, stream>>>(edge3, E3c, pseudo3, cube3, binCnt3, cntD3);
    bin_plan<<<1, 64, 0, stream>>>(binCnt3, binStart3, blkPrefix3, chunkBin3, chunkOff3);
    bin_scatter<<<(E3c + 255) / 256, 256, 0, stream>>>(cube3, E3c, binStart3, cursor3, order3);
    scan_excl<<<1, 256, 0, stream>>>(cntD3, start3, N3c);
    key_scatter<<<(E3c + 255) / 256, 256, 0, stream>>>(edge3, E3c, 0, start3, curD3, eidx3);
    {
        int maxBlk = (E3c + 255) / 256 + 64;
        spline_gemm<128><<<dim3(maxBlk, 2), 256, 0, stream>>>(
            edge3, E3c, pseudo3, W3, xm3, order3, binStart3, binCnt3, blkPrefix3,
            chunkBin3, chunkOff3, msg3);
    }
    conv_gather128<<<(N3c + 3) / 4, 256, 0, stream>>>(msg3, start3, eidx3, xm3,
                                                      root3, b3, x3, N3c);

    // pool 3: x3 -> xm4 (512 x 128) == (64 x 1024)
    segmax_scatter<<<(N3c * 128) / 256, 256, 0, stream>>>(x3, cluster3, (unsigned*)xm4, N3c * 128, 7);
    segmax_decode<<<(512 * 128) / 256, 256, 0, stream>>>((unsigned*)xm4, 512 * 128);

    // FC head
    fc1_k<<<64, 256, 0, stream>>>(xm4, fc1_w, fc1_b, h1);
    fc2_k<<<64, 64, 0, stream>>>(h1, fc2_w, fc2_b, out);
}

// Round 6
// 809.080 us; speedup vs baseline: 1.7280x; 1.7280x over previous
//
#include <hip/hip_runtime.h>
#include <hip/hip_bf16.h>
#include <math.h>

#define N0c 120000
#define N1c 20000
#define N2c 6000
#define N3c 1600
#define Bc  64
#define E1c 480000
#define E2c 144000
#define E3c 38400

#define HB1 240   // hist blocks for conv1 (1250 bins of dst>>4)
#define HB2 120   // hist blocks for conv2 cube sort
#define HB3 40    // hist blocks for conv3 cube sort

__device__ __forceinline__ float eluf(float x) {
    return x > 0.0f ? x : expm1f(x);
}

// monotone float -> uint mapping for atomicMax-based segment max
__device__ __forceinline__ unsigned f2sort(float f) {
    unsigned u = __float_as_uint(f);
    return (u & 0x80000000u) ? ~u : (u | 0x80000000u);
}
__device__ __forceinline__ float sort2f(unsigned u) {
    unsigned bits = (u & 0x80000000u) ? (u & 0x7FFFFFFFu) : ~u;
    return __uint_as_float(bits);
}

__global__ void segmax_scatter(const float* __restrict__ x, const int* __restrict__ cl,
                               unsigned* __restrict__ buf, int total, int shiftC) {
    int idx = blockIdx.x * blockDim.x + threadIdx.x;
    if (idx >= total) return;
    int n = idx >> shiftC;
    int c = idx - (n << shiftC);
    atomicMax(&buf[(cl[n] << shiftC) + c], f2sort(x[idx]));
}

__global__ void segmax_decode(unsigned* __restrict__ buf, int total) {
    int idx = blockIdx.x * blockDim.x + threadIdx.x;
    if (idx >= total) return;
    float f = sort2f(buf[idx]);
    unsigned b = __float_as_uint(f);
    if ((b & 0x7F800000u) == 0x7F800000u) f = 0.0f;   // !isfinite -> 0
    ((float*)buf)[idx] = f;
}

// single-block exclusive scan, n up to ~6k
__global__ void scan_excl(const int* __restrict__ cnt, int* __restrict__ start, int n) {
    __shared__ int buf[256];
    __shared__ int carryS;
    int t = threadIdx.x;
    if (t == 0) carryS = 0;
    __syncthreads();
    for (int base = 0; base < n; base += 256) {
        int i = base + t;
        int v = (i < n) ? cnt[i] : 0;
        buf[t] = v;
        __syncthreads();
        for (int ofs = 1; ofs < 256; ofs <<= 1) {
            int add = (t >= ofs) ? buf[t - ofs] : 0;
            __syncthreads();
            buf[t] += add;
            __syncthreads();
        }
        if (i < n) start[i] = carryS + buf[t] - v;
        __syncthreads();
        if (t == 0) carryS += buf[255];
        __syncthreads();
    }
    if (t == 0) start[n] = carryS;
}

// dst-CSR scatter (uncontended: ~24 edges per dst)
__global__ void key_scatter(const int* __restrict__ edge, int E,
                            const int* __restrict__ start, int* __restrict__ cursor,
                            int* __restrict__ ord) {
    int e = blockIdx.x * blockDim.x + threadIdx.x;
    if (e >= E) return;
    int d = edge[E + e];
    int p = atomicAdd(&cursor[d], 1);
    ord[start[d] + p] = e;
}

// ---- conv1 counting sort by dst>>4 (1250 bins), LDS-aggregated ----

__global__ __launch_bounds__(256) void key_hist_lds(const int* __restrict__ edge, int E,
                                                    int* __restrict__ blockCnt) {
    __shared__ int h[1250];
    for (int i = threadIdx.x; i < 1250; i += 256) h[i] = 0;
    __syncthreads();
    for (int e = blockIdx.x * 256 + threadIdx.x; e < E; e += HB1 * 256)
        atomicAdd(&h[edge[E + e] >> 4], 1);
    __syncthreads();
    for (int i = threadIdx.x; i < 1250; i += 256)
        blockCnt[blockIdx.x * 1250 + i] = h[i];
}

__global__ void tot_k(const int* __restrict__ blockCnt, int nbins, int nblk,
                      int* __restrict__ tot) {
    int i = blockIdx.x * blockDim.x + threadIdx.x;
    if (i >= nbins) return;
    int s = 0;
    for (int b = 0; b < nblk; b++) s += blockCnt[b * nbins + i];
    tot[i] = s;
}

__global__ void off_k(const int* __restrict__ blockCnt, const int* __restrict__ binStart,
                      int nbins, int nblk, int* __restrict__ blockOff) {
    int i = blockIdx.x * blockDim.x + threadIdx.x;
    if (i >= nbins) return;
    int run = binStart[i];
    for (int b = 0; b < nblk; b++) {
        blockOff[b * nbins + i] = run;
        run += blockCnt[b * nbins + i];
    }
}

__global__ __launch_bounds__(256) void key_scatter_lds(const int* __restrict__ edge, int E,
                                                       const int* __restrict__ blockOff,
                                                       int* __restrict__ order) {
    __shared__ int cur[1250];
    for (int i = threadIdx.x; i < 1250; i += 256)
        cur[i] = blockOff[blockIdx.x * 1250 + i];
    __syncthreads();
    for (int e = blockIdx.x * 256 + threadIdx.x; e < E; e += HB1 * 256) {
        int p = atomicAdd(&cur[edge[E + e] >> 4], 1);
        order[p] = e;
    }
}

// ---- conv1 (C_in=1): per-16-node block, LDS knot accumulation + tiny GEMM ----
__global__ __launch_bounds__(256) void conv1_block(
    const int* __restrict__ edge, const float* __restrict__ pseudo,
    const float* __restrict__ x,
    const int* __restrict__ start, const int* __restrict__ order,
    const float* __restrict__ W, const float* __restrict__ root,
    const float* __restrict__ bias, float* __restrict__ out) {
    __shared__ float T[16][128];
    __shared__ int degL[16];
    int b = blockIdx.x;
    for (int j = threadIdx.x; j < 2048; j += 256) ((float*)T)[j] = 0.0f;
    if (threadIdx.x < 16) degL[threadIdx.x] = 0;
    __syncthreads();
    int s0 = start[b], s1 = start[b + 1];
    for (int i = s0 + threadIdx.x; i < s1; i += 256) {
        int e = order[i];
        int src = edge[e], dst = edge[E1c + e];
        int ln = dst & 15;
        float xv = x[src];
        float f[3];
        int loi[3];
        #pragma unroll
        for (int d = 0; d < 3; d++) {
            float pp = pseudo[e * 3 + d] * 4.0f;
            float l = fminf(fmaxf(floorf(pp), 0.0f), 3.0f);
            f[d] = pp - l;
            loi[d] = (int)l;
        }
        int kbase = loi[0] + 5 * loi[1] + 25 * loi[2];
        #pragma unroll
        for (int s = 0; s < 8; s++) {
            int b0 = s & 1, b1 = (s >> 1) & 1, b2 = (s >> 2) & 1;
            float w0 = b0 ? f[0] : 1.0f - f[0];
            float w1 = b1 ? f[1] : 1.0f - f[1];
            float w2 = b2 ? f[2] : 1.0f - f[2];
            int k = kbase + b0 + 5 * b1 + 25 * b2;
            atomicAdd(&T[ln][k], xv * w0 * w1 * w2);
        }
        atomicAdd(&degL[ln], 1);
    }
    __syncthreads();
    int w = threadIdx.x >> 6, lane = threadIdx.x & 63;
    float acc[4] = {0.0f, 0.0f, 0.0f, 0.0f};
    for (int k = 0; k < 125; k++) {
        float wv = W[(k << 6) + lane];
        #pragma unroll
        for (int j = 0; j < 4; j++)
            acc[j] = fmaf(T[w + 4 * j][k], wv, acc[j]);
    }
    int v0 = b << 4;
    #pragma unroll
    for (int j = 0; j < 4; j++) {
        int ln = w + 4 * j;
        int v = v0 + ln;
        float d = fmaxf((float)degL[ln], 1.0f);
        out[((size_t)v << 6) + lane] = eluf(acc[j] / d + x[v] * root[lane] + bias[lane]);
    }
}

// ---- conv2/conv3 counting sort by spline cube (64 bins), LDS-aggregated ----

// fused: cube compute + LDS cube hist + dst-degree hist (uncontended global)
__global__ __launch_bounds__(256) void bin_hist_v2(const int* __restrict__ edge, int E,
                                                   const float* __restrict__ pseudo,
                                                   int* __restrict__ cube,
                                                   int* __restrict__ blockCnt,
                                                   int* __restrict__ dstCnt, int nblk) {
    __shared__ int h[64];
    int t = threadIdx.x;
    if (t < 64) h[t] = 0;
    __syncthreads();
    for (int e = blockIdx.x * 256 + t; e < E; e += nblk * 256) {
        int c = 0, mul = 1;
        #pragma unroll
        for (int d = 0; d < 3; d++) {
            float p = pseudo[e * 3 + d] * 4.0f;
            float l = fminf(fmaxf(floorf(p), 0.0f), 3.0f);
            c += (int)l * mul;
            mul <<= 2;
        }
        cube[e] = c;
        atomicAdd(&h[c], 1);
        atomicAdd(&dstCnt[edge[E + e]], 1);
    }
    __syncthreads();
    if (t < 64) blockCnt[blockIdx.x * 64 + t] = h[t];
}

// one block, 64 threads: totals, bin starts, per-(block,bin) offsets, chunk map
__global__ void bin_plan_v2(const int* __restrict__ blockCnt, int nblk,
                            int* __restrict__ binCnt, int* __restrict__ binStart,
                            int* __restrict__ blockOff, int* __restrict__ blkPrefix,
                            int* __restrict__ chunkBin, int* __restrict__ chunkOff) {
    __shared__ int tot[64], ss[64], ps[64];
    int t = threadIdx.x;
    int sum = 0;
    for (int b = 0; b < nblk; b++) sum += blockCnt[b * 64 + t];
    tot[t] = sum;
    __syncthreads();
    if (t == 0) {
        int s = 0, p = 0;
        for (int c = 0; c < 64; c++) {
            ss[c] = s; ps[c] = p;
            s += tot[c];
            p += (tot[c] + 255) >> 8;
        }
        blkPrefix[64] = p;
    }
    __syncthreads();
    binCnt[t] = tot[t];
    binStart[t] = ss[t];
    blkPrefix[t] = ps[t];
    int run = ss[t];
    for (int b = 0; b < nblk; b++) {
        blockOff[b * 64 + t] = run;
        run += blockCnt[b * 64 + t];
    }
    int nch = (tot[t] + 255) >> 8;
    for (int j = 0; j < nch; j++) {
        chunkBin[ps[t] + j] = t;
        chunkOff[ps[t] + j] = j;
    }
}

__global__ __launch_bounds__(256) void bin_scatter_v2(const int* __restrict__ cube, int E,
                                                      const int* __restrict__ blockOff,
                                                      int* __restrict__ order, int nblk) {
    __shared__ int cur[64];
    int t = threadIdx.x;
    if (t < 64) cur[t] = blockOff[blockIdx.x * 64 + t];
    __syncthreads();
    for (int e = blockIdx.x * 256 + t; e < E; e += nblk * 256) {
        int p = atomicAdd(&cur[cube[e]], 1);
        order[p] = e;
    }
}

// Binned spline-conv GEMM v3: per-edge messages, NO atomics.
template<int COUT>
__global__ __launch_bounds__(256) void spline_gemm(
    const int* __restrict__ edge, int E,
    const float* __restrict__ pseudo,
    const float* __restrict__ W,
    const float* __restrict__ x,
    const int* __restrict__ order,
    const int* __restrict__ binStart,
    const int* __restrict__ binCnt,
    const int* __restrict__ blkPrefix,
    const int* __restrict__ chunkBin,
    const int* __restrict__ chunkOff,
    float* __restrict__ msg)
{
    __shared__ float Bs[16][64];
    __shared__ float Xs[4][16][64];
    __shared__ float bsS[4][64][8];
    __shared__ int eS[4][64];

    int b = blockIdx.x;
    if (b >= blkPrefix[64]) return;
    int c = chunkBin[b];
    int chunk = chunkOff[b];
    int cnt = binCnt[c];

    int w = threadIdx.x >> 6, lane = threadIdx.x & 63;
    int pos = chunk * 256 + w * 64 + lane;
    bool active = pos < cnt;
    int e = active ? order[binStart[c] + pos] : 0;

    int src = 0;
    float f0 = 0.0f, f1 = 0.0f, f2 = 0.0f;
    if (active) {
        src = edge[e];
        float p0 = pseudo[e * 3 + 0] * 4.0f;
        float p1 = pseudo[e * 3 + 1] * 4.0f;
        float p2 = pseudo[e * 3 + 2] * 4.0f;
        f0 = p0 - fminf(fmaxf(floorf(p0), 0.0f), 3.0f);
        f1 = p1 - fminf(fmaxf(floorf(p1), 0.0f), 3.0f);
        f2 = p2 - fminf(fmaxf(floorf(p2), 0.0f), 3.0f);
    }
    eS[w][lane] = e;
    #pragma unroll
    for (int t = 0; t < 8; t++) {
        float w0 = (t & 1) ? f0 : 1.0f - f0;
        float w1 = (t & 2) ? f1 : 1.0f - f1;
        float w2 = (t & 4) ? f2 : 1.0f - f2;
        bsS[w][lane][t] = active ? (w0 * w1 * w2) : 0.0f;
    }

    int lo0 = c & 3, lo1 = (c >> 2) & 3, lo2 = c >> 4;
    int kbase = lo0 + 5 * lo1 + 25 * lo2;
    int colOff = (COUT == 128) ? (blockIdx.y << 6) : 0;
    int tm = lane >> 3, tn = lane & 7;

    float acc[8][8];
    #pragma unroll
    for (int ii = 0; ii < 8; ii++)
        #pragma unroll
        for (int jj = 0; jj < 8; jj++) acc[ii][jj] = 0.0f;

    const float* xrow = x + ((size_t)src << 6);

    #pragma unroll 1
    for (int ic = 0; ic < 64; ic += 16) {
        __syncthreads();   // prev round's Bs & Xs fully consumed
        #pragma unroll
        for (int r = 0; r < 16; r += 4) {
            float4 xq = *(const float4*)(xrow + ic + r);
            Xs[w][r + 0][lane] = xq.x;
            Xs[w][r + 1][lane] = xq.y;
            Xs[w][r + 2][lane] = xq.z;
            Xs[w][r + 3][lane] = xq.w;
        }
        #pragma unroll 1
        for (int t = 0; t < 8; t++) {
            int k = kbase + (t & 1) + 5 * ((t >> 1) & 1) + 25 * (t >> 2);
            const float* Wk = W + (size_t)k * 64 * COUT + colOff;
            if (t > 0) __syncthreads();   // Bs consumed by all waves
            #pragma unroll
            for (int r = w; r < 16; r += 4)
                Bs[r][lane] = Wk[(size_t)(ic + r) * COUT + lane];
            __syncthreads();
            float bsf[8];
            #pragma unroll
            for (int ii = 0; ii < 8; ii++) bsf[ii] = bsS[w][tm * 8 + ii][t];
            #pragma unroll
            for (int r = 0; r < 16; r++) {
                float4 a0 = *(const float4*)(&Xs[w][r][tm * 8]);
                float4 a1 = *(const float4*)(&Xs[w][r][tm * 8 + 4]);
                float4 b0 = *(const float4*)(&Bs[r][tn * 8]);
                float4 b1 = *(const float4*)(&Bs[r][tn * 8 + 4]);
                float av[8] = {a0.x * bsf[0], a0.y * bsf[1], a0.z * bsf[2], a0.w * bsf[3],
                               a1.x * bsf[4], a1.y * bsf[5], a1.z * bsf[6], a1.w * bsf[7]};
                float bv[8] = {b0.x, b0.y, b0.z, b0.w, b1.x, b1.y, b1.z, b1.w};
                #pragma unroll
                for (int ii = 0; ii < 8; ii++)
                    #pragma unroll
                    for (int jj = 0; jj < 8; jj++)
                        acc[ii][jj] = fmaf(av[ii], bv[jj], acc[ii][jj]);
            }
        }
    }

    // Epilogue: wave-private transpose through Xs[w], coalesced msg stores.
    #pragma unroll 1
    for (int pass = 0; pass < 4; pass++) {
        if ((tm >> 1) == pass) {
            int rl = (tm & 1) * 8;
            #pragma unroll
            for (int ii = 0; ii < 8; ii++) {
                *(float4*)(&Xs[w][rl + ii][tn * 8]) =
                    make_float4(acc[ii][0], acc[ii][1], acc[ii][2], acc[ii][3]);
                *(float4*)(&Xs[w][rl + ii][tn * 8 + 4]) =
                    make_float4(acc[ii][4], acc[ii][5], acc[ii][6], acc[ii][7]);
            }
        }
        __builtin_amdgcn_wave_barrier();
        int rowBase = chunk * 256 + w * 64 + pass * 16;
        #pragma unroll 1
        for (int r = 0; r < 16; r++) {
            if (rowBase + r < cnt) {
                msg[(size_t)eS[w][pass * 16 + r] * COUT + colOff + lane] = Xs[w][r][lane];
            }
        }
        __builtin_amdgcn_wave_barrier();
    }
}

// dst-CSR gather + fused node update, COUT=64. One wave per node.
__global__ __launch_bounds__(256) void conv_gather64(
    const float* __restrict__ msg, const int* __restrict__ start,
    const int* __restrict__ eidx, const float* __restrict__ xm,
    const float* __restrict__ root, const float* __restrict__ bias,
    float* __restrict__ out, int nNodes) {
    __shared__ float xsh[4][64];
    int w = threadIdx.x >> 6, lane = threadIdx.x & 63;
    int v = blockIdx.x * 4 + w;
    if (v >= nNodes) return;
    xsh[w][lane] = xm[((size_t)v << 6) + lane];
    int s0 = start[v], s1 = start[v + 1];
    float acc = 0.0f;
    int p = s0;
    for (; p + 1 < s1; p += 2) {
        int e0 = eidx[p], e1 = eidx[p + 1];
        acc += msg[((size_t)e0 << 6) + lane] + msg[((size_t)e1 << 6) + lane];
    }
    if (p < s1) acc += msg[((size_t)eidx[p] << 6) + lane];
    acc /= fmaxf((float)(s1 - s0), 1.0f);
    float r = 0.0f;
    #pragma unroll 8
    for (int i = 0; i < 64; i++)
        r = fmaf(xsh[w][i], root[(i << 6) + lane], r);
    out[((size_t)v << 6) + lane] = eluf(acc + r + bias[lane]);
}

// dst-CSR gather + fused node update, COUT=128. One wave per node (2 ch/lane).
__global__ __launch_bounds__(256) void conv_gather128(
    const float* __restrict__ msg, const int* __restrict__ start,
    const int* __restrict__ eidx, const float* __restrict__ xm,
    const float* __restrict__ root, const float* __restrict__ bias,
    float* __restrict__ out, int nNodes) {
    __shared__ float xsh[4][64];
    int w = threadIdx.x >> 6, lane = threadIdx.x & 63;
    int v = blockIdx.x * 4 + w;
    if (v >= nNodes) return;
    xsh[w][lane] = xm[((size_t)v << 6) + lane];
    int s0 = start[v], s1 = start[v + 1];
    float acc0 = 0.0f, acc1 = 0.0f;
    for (int p = s0; p < s1; p++) {
        const float* mrow = msg + ((size_t)eidx[p] << 7);
        acc0 += mrow[lane];
        acc1 += mrow[lane + 64];
    }
    float dinv = 1.0f / fmaxf((float)(s1 - s0), 1.0f);
    acc0 *= dinv; acc1 *= dinv;
    float r0 = 0.0f, r1 = 0.0f;
    #pragma unroll 8
    for (int i = 0; i < 64; i++) {
        float xi = xsh[w][i];
        r0 = fmaf(xi, root[(i << 7) + lane], r0);
        r1 = fmaf(xi, root[(i << 7) + 64 + lane], r1);
    }
    out[((size_t)v << 7) + lane] = eluf(acc0 + r0 + bias[lane]);
    out[((size_t)v << 7) + 64 + lane] = eluf(acc1 + r1 + bias[lane + 64]);
}

__global__ void fc1_k(const float* __restrict__ xin, const float* __restrict__ w,
                      const float* __restrict__ b, float* __restrict__ h) {
    __shared__ float xsh[1024];
    int row = blockIdx.x;
    for (int i = threadIdx.x; i < 1024; i += 256) xsh[i] = xin[row * 1024 + i];
    __syncthreads();
    int o = threadIdx.x;
    float acc = b[o];
    #pragma unroll 8
    for (int i = 0; i < 1024; i++) acc = fmaf(xsh[i], w[i * 256 + o], acc);
    h[row * 256 + o] = eluf(acc);
}

__global__ void fc2_k(const float* __restrict__ h, const float* __restrict__ w,
                      const float* __restrict__ b, float* __restrict__ out) {
    __shared__ float hs[256];
    __shared__ float lg[10];
    int row = blockIdx.x;
    int t = threadIdx.x;
    for (int i = t; i < 256; i += 64) hs[i] = h[row * 256 + i];
    __syncthreads();
    if (t < 10) {
        float acc = b[t];
        for (int i = 0; i < 256; i++) acc = fmaf(hs[i], w[i * 10 + t], acc);
        lg[t] = acc;
    }
    __syncthreads();
    if (t < 10) {
        float m = -1e30f;
        #pragma unroll
        for (int j = 0; j < 10; j++) m = fmaxf(m, lg[j]);
        float sum = 0.0f;
        #pragma unroll
        for (int j = 0; j < 10; j++) sum += expf(lg[j] - m);
        out[row * 10 + t] = lg[t] - m - logf(sum);
    }
}

extern "C" void kernel_launch(void* const* d_in, const int* in_sizes, int n_in,
                              void* d_out, int out_size, void* d_ws, size_t ws_size,
                              hipStream_t stream) {
    const float* x0      = (const float*)d_in[0];
    const int*   cluster0= (const int*)d_in[1];
    const int*   edge1   = (const int*)d_in[2];
    const float* pseudo1 = (const float*)d_in[3];
    const float* W1      = (const float*)d_in[4];
    const float* root1   = (const float*)d_in[5];
    const float* b1      = (const float*)d_in[6];
    const int*   cluster1= (const int*)d_in[7];
    const int*   edge2   = (const int*)d_in[8];
    const float* pseudo2 = (const float*)d_in[9];
    const float* W2      = (const float*)d_in[10];
    const float* root2   = (const float*)d_in[11];
    const float* b2      = (const float*)d_in[12];
    const int*   cluster2= (const int*)d_in[13];
    const int*   edge3   = (const int*)d_in[14];
    const float* pseudo3 = (const float*)d_in[15];
    const float* W3      = (const float*)d_in[16];
    const float* root3   = (const float*)d_in[17];
    const float* b3      = (const float*)d_in[18];
    const int*   cluster3= (const int*)d_in[19];
    const float* fc1_w   = (const float*)d_in[20];
    const float* fc1_b   = (const float*)d_in[21];
    const float* fc2_w   = (const float*)d_in[22];
    const float* fc2_b   = (const float*)d_in[23];
    float* out = (float*)d_out;

    float* ws = (float*)d_ws;
    size_t off = 0;
    // ---- zeroed region ----
    float* xm1  = ws + off; off += 20480;
    float* xm2  = ws + off; off += (size_t)N2c * 64;
    float* xm3  = ws + off; off += (size_t)N3c * 64;
    float* xm4  = ws + off; off += 512 * 128;
    int* cntD2   = (int*)(ws + off); off += 6016;
    int* curD2   = (int*)(ws + off); off += 6016;
    int* cntD3   = (int*)(ws + off); off += 1664;
    int* curD3   = (int*)(ws + off); off += 1664;
    size_t zeroFloats = off;
    // ---- non-zeroed region (fully written before read every launch) ----
    float* x1   = ws + off; off += (size_t)N1c * 64;
    float* x2   = ws + off; off += (size_t)N2c * 64;
    float* x3   = ws + off; off += (size_t)N3c * 128;
    float* h1   = ws + off; off += 64 * 256;
    int* cube2     = (int*)(ws + off); off += E2c;
    int* order2    = (int*)(ws + off); off += E2c;
    int* cube3     = (int*)(ws + off); off += E3c;
    int* order3    = (int*)(ws + off); off += E3c;
    int* eidx2     = (int*)(ws + off); off += E2c;
    int* start2    = (int*)(ws + off); off += 6016;
    int* eidx3     = (int*)(ws + off); off += E3c;
    int* start3    = (int*)(ws + off); off += 1664;
    int* start1    = (int*)(ws + off); off += 1280;
    int* tot1      = (int*)(ws + off); off += 1280;
    int* blockCnt1 = (int*)(ws + off); off += HB1 * 1250;
    int* blockOff1 = (int*)(ws + off); off += HB1 * 1250;
    int* blockCnt2 = (int*)(ws + off); off += HB2 * 64;
    int* blockOff2 = (int*)(ws + off); off += HB2 * 64;
    int* blockCnt3 = (int*)(ws + off); off += HB3 * 64;
    int* blockOff3 = (int*)(ws + off); off += HB3 * 64;
    int* binCnt2   = (int*)(ws + off); off += 64;
    int* binStart2 = (int*)(ws + off); off += 64;
    int* blkPrefix2= (int*)(ws + off); off += 80;
    int* chunkBin2 = (int*)(ws + off); off += 704;
    int* chunkOff2 = (int*)(ws + off); off += 704;
    int* binCnt3   = (int*)(ws + off); off += 64;
    int* binStart3 = (int*)(ws + off); off += 64;
    int* blkPrefix3= (int*)(ws + off); off += 80;
    int* chunkBin3 = (int*)(ws + off); off += 256;
    int* chunkOff3 = (int*)(ws + off); off += 256;
    // big scratch: order1 (conv1) -> msg2 (conv2) -> msg3 (conv3), serially reused
    float* big  = ws + off; off += (size_t)E2c * 64;   // 9.216M floats (largest user)
    int*   order1 = (int*)big;
    float* msg2   = big;
    float* msg3   = big;

    hipMemsetAsync(d_ws, 0, zeroFloats * sizeof(float), stream);

    // pool 0: x0 -> xm1 (N1 x 1)
    segmax_scatter<<<(N0c + 255) / 256, 256, 0, stream>>>(x0, cluster0, (unsigned*)xm1, N0c, 0);
    segmax_decode<<<(N1c + 255) / 256, 256, 0, stream>>>((unsigned*)xm1, N1c);

    // conv1 (1 -> 64): LDS counting sort by dst>>4, per-16-node LDS accumulation
    key_hist_lds<<<HB1, 256, 0, stream>>>(edge1, E1c, blockCnt1);
    tot_k<<<5, 256, 0, stream>>>(blockCnt1, 1250, HB1, tot1);
    scan_excl<<<1, 256, 0, stream>>>(tot1, start1, 1250);
    off_k<<<5, 256, 0, stream>>>(blockCnt1, start1, 1250, HB1, blockOff1);
    key_scatter_lds<<<HB1, 256, 0, stream>>>(edge1, E1c, blockOff1, order1);
    conv1_block<<<1250, 256, 0, stream>>>(edge1, pseudo1, xm1, start1, order1,
                                          W1, root1, b1, x1);

    // pool 1: x1 -> xm2 (N2 x 64)
    segmax_scatter<<<(N1c * 64) / 256, 256, 0, stream>>>(x1, cluster1, (unsigned*)xm2, N1c * 64, 6);
    segmax_decode<<<(N2c * 64) / 256, 256, 0, stream>>>((unsigned*)xm2, N2c * 64);

    // conv2 (64 -> 64): LDS cube sort -> GEMM -> msg -> dst-CSR gather
    bin_hist_v2<<<HB2, 256, 0, stream>>>(edge2, E2c, pseudo2, cube2, blockCnt2, cntD2, HB2);
    bin_plan_v2<<<1, 64, 0, stream>>>(blockCnt2, HB2, binCnt2, binStart2, blockOff2,
                                      blkPrefix2, chunkBin2, chunkOff2);
    bin_scatter_v2<<<HB2, 256, 0, stream>>>(cube2, E2c, blockOff2, order2, HB2);
    scan_excl<<<1, 256, 0, stream>>>(cntD2, start2, N2c);
    key_scatter<<<(E2c + 255) / 256, 256, 0, stream>>>(edge2, E2c, start2, curD2, eidx2);
    {
        int maxBlk = (E2c + 255) / 256 + 64;
        spline_gemm<64><<<dim3(maxBlk, 1), 256, 0, stream>>>(
            edge2, E2c, pseudo2, W2, xm2, order2, binStart2, binCnt2, blkPrefix2,
            chunkBin2, chunkOff2, msg2);
    }
    conv_gather64<<<(N2c + 3) / 4, 256, 0, stream>>>(msg2, start2, eidx2, xm2,
                                                     root2, b2, x2, N2c);

    // pool 2: x2 -> xm3 (N3 x 64)
    segmax_scatter<<<(N2c * 64) / 256, 256, 0, stream>>>(x2, cluster2, (unsigned*)xm3, N2c * 64, 6);
    segmax_decode<<<(N3c * 64) / 256, 256, 0, stream>>>((unsigned*)xm3, N3c * 64);

    // conv3 (64 -> 128): LDS cube sort -> GEMM -> msg -> dst-CSR gather
    bin_hist_v2<<<HB3, 256, 0, stream>>>(edge3, E3c, pseudo3, cube3, blockCnt3, cntD3, HB3);
    bin_plan_v2<<<1, 64, 0, stream>>>(blockCnt3, HB3, binCnt3, binStart3, blockOff3,
                                      blkPrefix3, chunkBin3, chunkOff3);
    bin_scatter_v2<<<HB3, 256, 0, stream>>>(cube3, E3c, blockOff3, order3, HB3);
    scan_excl<<<1, 256, 0, stream>>>(cntD3, start3, N3c);
    key_scatter<<<(E3c + 255) / 256, 256, 0, stream>>>(edge3, E3c, start3, curD3, eidx3);
    {
        int maxBlk = (E3c + 255) / 256 + 64;
        spline_gemm<128><<<dim3(maxBlk, 2), 256, 0, stream>>>(
            edge3, E3c, pseudo3, W3, xm3, order3, binStart3, binCnt3, blkPrefix3,
            chunkBin3, chunkOff3, msg3);
    }
    conv_gather128<<<(N3c + 3) / 4, 256, 0, stream>>>(msg3, start3, eidx3, xm3,
                                                      root3, b3, x3, N3c);

    // pool 3: x3 -> xm4 (512 x 128) == (64 x 1024)
    segmax_scatter<<<(N3c * 128) / 256, 256, 0, stream>>>(x3, cluster3, (unsigned*)xm4, N3c * 128, 7);
    segmax_decode<<<(512 * 128) / 256, 256, 0, stream>>>((unsigned*)xm4, 512 * 128);

    // FC head
    fc1_k<<<64, 256, 0, stream>>>(xm4, fc1_w, fc1_b, h1);
    fc2_k<<<64, 64, 0, stream>>>(h1, fc2_w, fc2_b, out);
}

// Round 7
// 671.026 us; speedup vs baseline: 2.0835x; 1.2057x over previous
//
#include <hip/hip_runtime.h>
#include <hip/hip_bf16.h>
#include <math.h>

#define N0c 120000
#define N1c 20000
#define N2c 6000
#define N3c 1600
#define Bc  64
#define E1c 480000
#define E2c 144000
#define E3c 38400

#define HB1 128   // hist blocks for conv1 (1250 bins of dst>>4)
#define HB2 120   // hist blocks for conv2 cube sort
#define HB3 40    // hist blocks for conv3 cube sort

__device__ __forceinline__ float eluf(float x) {
    return x > 0.0f ? x : expm1f(x);
}

// monotone float -> uint mapping for atomicMax-based segment max
__device__ __forceinline__ unsigned f2sort(float f) {
    unsigned u = __float_as_uint(f);
    return (u & 0x80000000u) ? ~u : (u | 0x80000000u);
}
__device__ __forceinline__ float sort2f(unsigned u) {
    unsigned bits = (u & 0x80000000u) ? (u & 0x7FFFFFFFu) : ~u;
    return __uint_as_float(bits);
}

__global__ void segmax_scatter(const float* __restrict__ x, const int* __restrict__ cl,
                               unsigned* __restrict__ buf, int total, int shiftC) {
    int idx = blockIdx.x * blockDim.x + threadIdx.x;
    if (idx >= total) return;
    int n = idx >> shiftC;
    int c = idx - (n << shiftC);
    atomicMax(&buf[(cl[n] << shiftC) + c], f2sort(x[idx]));
}

__global__ void segmax_decode(unsigned* __restrict__ buf, int total) {
    int idx = blockIdx.x * blockDim.x + threadIdx.x;
    if (idx >= total) return;
    float f = sort2f(buf[idx]);
    unsigned b = __float_as_uint(f);
    if ((b & 0x7F800000u) == 0x7F800000u) f = 0.0f;   // !isfinite -> 0
    ((float*)buf)[idx] = f;
}

// single-block exclusive scan, items-per-thread + one LDS scan
__global__ __launch_bounds__(256) void scan_excl(const int* __restrict__ cnt,
                                                 int* __restrict__ start, int n) {
    __shared__ int ps[256];
    int t = threadIdx.x;
    int items = (n + 255) >> 8;
    int base = t * items;
    int s = 0;
    for (int i = 0; i < items; i++) {
        int idx = base + i;
        if (idx < n) s += cnt[idx];
    }
    ps[t] = s;
    __syncthreads();
    for (int ofs = 1; ofs < 256; ofs <<= 1) {
        int add = (t >= ofs) ? ps[t - ofs] : 0;
        __syncthreads();
        ps[t] += add;
        __syncthreads();
    }
    int run = (t == 0) ? 0 : ps[t - 1];
    for (int i = 0; i < items; i++) {
        int idx = base + i;
        if (idx < n) { start[idx] = run; run += cnt[idx]; }
    }
    if (t == 255) start[n] = run;
}

// dst-CSR scatter (uncontended: ~24 edges per dst)
__global__ void key_scatter(const int* __restrict__ edge, int E,
                            const int* __restrict__ start, int* __restrict__ cursor,
                            int* __restrict__ ord) {
    int e = blockIdx.x * blockDim.x + threadIdx.x;
    if (e >= E) return;
    int d = edge[E + e];
    int p = atomicAdd(&cursor[d], 1);
    ord[start[d] + p] = e;
}

// ---- conv1 counting sort by dst>>4 (1250 bins), LDS-aggregated ----

__global__ __launch_bounds__(256) void key_hist_lds(const int* __restrict__ edge, int E,
                                                    int* __restrict__ blockCnt) {
    __shared__ int h[1250];
    for (int i = threadIdx.x; i < 1250; i += 256) h[i] = 0;
    __syncthreads();
    for (int e = blockIdx.x * 256 + threadIdx.x; e < E; e += HB1 * 256)
        atomicAdd(&h[edge[E + e] >> 4], 1);
    __syncthreads();
    for (int i = threadIdx.x; i < 1250; i += 256)
        blockCnt[blockIdx.x * 1250 + i] = h[i];
}

__global__ void tot_k(const int* __restrict__ blockCnt, int nbins, int nblk,
                      int* __restrict__ tot) {
    int i = blockIdx.x * blockDim.x + threadIdx.x;
    if (i >= nbins) return;
    int s = 0;
    for (int b = 0; b < nblk; b++) s += blockCnt[b * nbins + i];
    tot[i] = s;
}

__global__ void off_k(const int* __restrict__ blockCnt, const int* __restrict__ binStart,
                      int nbins, int nblk, int* __restrict__ blockOff) {
    int i = blockIdx.x * blockDim.x + threadIdx.x;
    if (i >= nbins) return;
    int run = binStart[i];
    for (int b = 0; b < nblk; b++) {
        blockOff[b * nbins + i] = run;
        run += blockCnt[b * nbins + i];
    }
}

__global__ __launch_bounds__(256) void key_scatter_lds(const int* __restrict__ edge, int E,
                                                       const int* __restrict__ blockOff,
                                                       int* __restrict__ order) {
    __shared__ int cur[1250];
    for (int i = threadIdx.x; i < 1250; i += 256)
        cur[i] = blockOff[blockIdx.x * 1250 + i];
    __syncthreads();
    for (int e = blockIdx.x * 256 + threadIdx.x; e < E; e += HB1 * 256) {
        int p = atomicAdd(&cur[edge[E + e] >> 4], 1);
        order[p] = e;
    }
}

// ---- conv1 (C_in=1): per-16-node block, LDS knot accumulation + tiny GEMM ----
// Epilogue fused with pool1: atomicMax into xm2 (sortable-uint).
__global__ __launch_bounds__(256) void conv1_block(
    const int* __restrict__ edge, const float* __restrict__ pseudo,
    const float* __restrict__ x,
    const int* __restrict__ start, const int* __restrict__ order,
    const float* __restrict__ W, const float* __restrict__ root,
    const float* __restrict__ bias, const int* __restrict__ cl,
    unsigned* __restrict__ xmOut) {
    __shared__ float T[16][128];
    __shared__ int degL[16];
    int b = blockIdx.x;
    for (int j = threadIdx.x; j < 2048; j += 256) ((float*)T)[j] = 0.0f;
    if (threadIdx.x < 16) degL[threadIdx.x] = 0;
    __syncthreads();
    int s0 = start[b], s1 = start[b + 1];
    for (int i = s0 + threadIdx.x; i < s1; i += 256) {
        int e = order[i];
        int src = edge[e], dst = edge[E1c + e];
        int ln = dst & 15;
        float xv = x[src];
        float f[3];
        int loi[3];
        #pragma unroll
        for (int d = 0; d < 3; d++) {
            float pp = pseudo[e * 3 + d] * 4.0f;
            float l = fminf(fmaxf(floorf(pp), 0.0f), 3.0f);
            f[d] = pp - l;
            loi[d] = (int)l;
        }
        int kbase = loi[0] + 5 * loi[1] + 25 * loi[2];
        #pragma unroll
        for (int s = 0; s < 8; s++) {
            int b0 = s & 1, b1 = (s >> 1) & 1, b2 = (s >> 2) & 1;
            float w0 = b0 ? f[0] : 1.0f - f[0];
            float w1 = b1 ? f[1] : 1.0f - f[1];
            float w2 = b2 ? f[2] : 1.0f - f[2];
            int k = kbase + b0 + 5 * b1 + 25 * b2;
            atomicAdd(&T[ln][k], xv * w0 * w1 * w2);
        }
        atomicAdd(&degL[ln], 1);
    }
    __syncthreads();
    int w = threadIdx.x >> 6, lane = threadIdx.x & 63;
    float acc[4] = {0.0f, 0.0f, 0.0f, 0.0f};
    for (int k = 0; k < 125; k++) {
        float wv = W[(k << 6) + lane];
        #pragma unroll
        for (int j = 0; j < 4; j++)
            acc[j] = fmaf(T[w + 4 * j][k], wv, acc[j]);
    }
    int v0 = b << 4;
    #pragma unroll
    for (int j = 0; j < 4; j++) {
        int ln = w + 4 * j;
        int v = v0 + ln;
        float d = fmaxf((float)degL[ln], 1.0f);
        float val = eluf(acc[j] / d + x[v] * root[lane] + bias[lane]);
        atomicMax(&xmOut[((size_t)cl[v] << 6) + lane], f2sort(val));
    }
}

// ---- conv2/conv3 counting sort by spline cube (64 bins), LDS-aggregated ----

__global__ __launch_bounds__(256) void bin_hist_v2(const int* __restrict__ edge, int E,
                                                   const float* __restrict__ pseudo,
                                                   int* __restrict__ cube,
                                                   int* __restrict__ blockCnt,
                                                   int* __restrict__ dstCnt, int nblk) {
    __shared__ int h[64];
    int t = threadIdx.x;
    if (t < 64) h[t] = 0;
    __syncthreads();
    for (int e = blockIdx.x * 256 + t; e < E; e += nblk * 256) {
        int c = 0, mul = 1;
        #pragma unroll
        for (int d = 0; d < 3; d++) {
            float p = pseudo[e * 3 + d] * 4.0f;
            float l = fminf(fmaxf(floorf(p), 0.0f), 3.0f);
            c += (int)l * mul;
            mul <<= 2;
        }
        cube[e] = c;
        atomicAdd(&h[c], 1);
        atomicAdd(&dstCnt[edge[E + e]], 1);
    }
    __syncthreads();
    if (t < 64) blockCnt[blockIdx.x * 64 + t] = h[t];
}

// one block, 64 threads: totals, bin starts, per-(block,bin) offsets, chunk map
// Chunk granularity = 128 edges (4 waves x 32).
__global__ void bin_plan_v2(const int* __restrict__ blockCnt, int nblk,
                            int* __restrict__ binCnt, int* __restrict__ binStart,
                            int* __restrict__ blockOff, int* __restrict__ blkPrefix,
                            int* __restrict__ chunkBin, int* __restrict__ chunkOff) {
    __shared__ int tot[64], ss[64], ps[64];
    int t = threadIdx.x;
    int sum = 0;
    for (int b = 0; b < nblk; b++) sum += blockCnt[b * 64 + t];
    tot[t] = sum;
    __syncthreads();
    if (t == 0) {
        int s = 0, p = 0;
        for (int c = 0; c < 64; c++) {
            ss[c] = s; ps[c] = p;
            s += tot[c];
            p += (tot[c] + 127) >> 7;
        }
        blkPrefix[64] = p;
    }
    __syncthreads();
    binCnt[t] = tot[t];
    binStart[t] = ss[t];
    blkPrefix[t] = ps[t];
    int run = ss[t];
    for (int b = 0; b < nblk; b++) {
        blockOff[b * 64 + t] = run;
        run += blockCnt[b * 64 + t];
    }
    int nch = (tot[t] + 127) >> 7;
    for (int j = 0; j < nch; j++) {
        chunkBin[ps[t] + j] = t;
        chunkOff[ps[t] + j] = j;
    }
}

__global__ __launch_bounds__(256) void bin_scatter_v2(const int* __restrict__ cube, int E,
                                                      const int* __restrict__ blockOff,
                                                      int* __restrict__ order, int nblk) {
    __shared__ int cur[64];
    int t = threadIdx.x;
    if (t < 64) cur[t] = blockOff[blockIdx.x * 64 + t];
    __syncthreads();
    for (int e = blockIdx.x * 256 + t; e < E; e += nblk * 256) {
        int p = atomicAdd(&cur[cube[e]], 1);
        order[p] = e;
    }
}

// Binned spline-conv GEMM v4: fully independent waves, no __syncthreads.
// Wave = 32 edges x 64 out-cols, acc 4x8/thread, K = 8 taps x 64 ic.
// Each wave stages its own Xs/Bs/bsS in a private LDS slice.
template<int COUT>
__global__ __launch_bounds__(256) void spline_gemm(
    const int* __restrict__ edge, int E,
    const float* __restrict__ pseudo,
    const float* __restrict__ W,
    const float* __restrict__ x,
    const int* __restrict__ order,
    const int* __restrict__ binStart,
    const int* __restrict__ binCnt,
    const int* __restrict__ blkPrefix,
    const int* __restrict__ chunkBin,
    const int* __restrict__ chunkOff,
    float* __restrict__ msg)
{
    __shared__ float Xs[4][16][32];
    __shared__ float Bs[4][16][64];
    __shared__ float bsS[4][8][32];   // t-major: conflict-free reads
    __shared__ int eS[4][32];

    int b = blockIdx.x;
    if (b >= blkPrefix[64]) return;
    int c = chunkBin[b];
    int chunk = chunkOff[b];
    int cnt = binCnt[c];

    int w = threadIdx.x >> 6, lane = threadIdx.x & 63;
    int el = lane & 31;       // edge slot within wave
    int half = lane >> 5;     // 0/1: which 4 taps this lane's basis covers
    int pos = chunk * 128 + w * 32 + el;
    bool active = pos < cnt;
    int e = active ? order[binStart[c] + pos] : 0;
    int src = active ? edge[e] : 0;
    if (half == 0) eS[w][el] = e;
    float f0 = 0.0f, f1 = 0.0f, f2 = 0.0f;
    if (active) {
        float p0 = pseudo[e * 3 + 0] * 4.0f;
        float p1 = pseudo[e * 3 + 1] * 4.0f;
        float p2 = pseudo[e * 3 + 2] * 4.0f;
        f0 = p0 - fminf(fmaxf(floorf(p0), 0.0f), 3.0f);
        f1 = p1 - fminf(fmaxf(floorf(p1), 0.0f), 3.0f);
        f2 = p2 - fminf(fmaxf(floorf(p2), 0.0f), 3.0f);
    }
    #pragma unroll
    for (int j = 0; j < 4; j++) {
        int t = half * 4 + j;
        float w0 = (t & 1) ? f0 : 1.0f - f0;
        float w1 = (t & 2) ? f1 : 1.0f - f1;
        float w2 = (t & 4) ? f2 : 1.0f - f2;
        bsS[w][t][el] = active ? (w0 * w1 * w2) : 0.0f;
    }

    int lo0 = c & 3, lo1 = (c >> 2) & 3, lo2 = c >> 4;
    int kbase = lo0 + 5 * lo1 + 25 * lo2;
    int colOff = (COUT == 128) ? (blockIdx.y << 6) : 0;
    int tm = lane >> 3, tn = lane & 7;

    float acc[4][8];
    #pragma unroll
    for (int ii = 0; ii < 4; ii++)
        #pragma unroll
        for (int jj = 0; jj < 8; jj++) acc[ii][jj] = 0.0f;

    #pragma unroll 1
    for (int ic = 0; ic < 64; ic += 16) {
        __builtin_amdgcn_wave_barrier();   // prior reads ordered before overwrite
        // stage Xs[16][32] transposed: lane loads its edge's 8 x-values
        {
            const float* xr = x + ((size_t)src << 6) + ic + (half << 3);
            float4 xa = *(const float4*)xr;
            float4 xb = *(const float4*)(xr + 4);
            int rb = half << 3;
            Xs[w][rb + 0][el] = xa.x;
            Xs[w][rb + 1][el] = xa.y;
            Xs[w][rb + 2][el] = xa.z;
            Xs[w][rb + 3][el] = xa.w;
            Xs[w][rb + 4][el] = xb.x;
            Xs[w][rb + 5][el] = xb.y;
            Xs[w][rb + 6][el] = xb.z;
            Xs[w][rb + 7][el] = xb.w;
        }
        #pragma unroll 1
        for (int t = 0; t < 8; t++) {
            int k = kbase + (t & 1) + 5 * ((t >> 1) & 1) + 25 * (t >> 2);
            const float* Wk = W + (size_t)k * 64 * COUT + colOff;
            __builtin_amdgcn_wave_barrier();   // prior Bs reads before overwrite
            #pragma unroll
            for (int r = 0; r < 16; r++)
                Bs[w][r][lane] = Wk[(size_t)(ic + r) * COUT + lane];
            __builtin_amdgcn_wave_barrier();   // writes before reads
            float bsf[4];
            #pragma unroll
            for (int ii = 0; ii < 4; ii++) bsf[ii] = bsS[w][t][tm * 4 + ii];
            #pragma unroll
            for (int r = 0; r < 16; r++) {
                float4 xq = *(const float4*)(&Xs[w][r][tm * 4]);
                float4 b0 = *(const float4*)(&Bs[w][r][tn * 8]);
                float4 b1 = *(const float4*)(&Bs[w][r][tn * 8 + 4]);
                float av[4] = {xq.x * bsf[0], xq.y * bsf[1], xq.z * bsf[2], xq.w * bsf[3]};
                float bv[8] = {b0.x, b0.y, b0.z, b0.w, b1.x, b1.y, b1.z, b1.w};
                #pragma unroll
                for (int ii = 0; ii < 4; ii++)
                    #pragma unroll
                    for (int jj = 0; jj < 8; jj++)
                        acc[ii][jj] = fmaf(av[ii], bv[jj], acc[ii][jj]);
            }
        }
    }

    // Epilogue: 2 passes of 16 rows through Bs[w], coalesced msg stores.
    int rowBase = chunk * 128 + w * 32;
    #pragma unroll 1
    for (int p = 0; p < 2; p++) {
        __builtin_amdgcn_wave_barrier();
        if ((tm >> 2) == p) {
            int rl = (tm & 3) * 4;
            #pragma unroll
            for (int ii = 0; ii < 4; ii++) {
                *(float4*)(&Bs[w][rl + ii][tn * 8]) =
                    make_float4(acc[ii][0], acc[ii][1], acc[ii][2], acc[ii][3]);
                *(float4*)(&Bs[w][rl + ii][tn * 8 + 4]) =
                    make_float4(acc[ii][4], acc[ii][5], acc[ii][6], acc[ii][7]);
            }
        }
        __builtin_amdgcn_wave_barrier();
        #pragma unroll 1
        for (int r = 0; r < 16; r++) {
            int row = p * 16 + r;
            if (rowBase + row < cnt)
                msg[(size_t)eS[w][row] * COUT + colOff + lane] = Bs[w][r][lane];
        }
    }
}

// dst-CSR gather + fused node update + fused pool scatter, COUT=64.
__global__ __launch_bounds__(256) void conv_gather64(
    const float* __restrict__ msg, const int* __restrict__ start,
    const int* __restrict__ eidx, const float* __restrict__ xm,
    const float* __restrict__ root, const float* __restrict__ bias,
    const int* __restrict__ cl, unsigned* __restrict__ xmOut, int nNodes) {
    __shared__ float xsh[4][64];
    int w = threadIdx.x >> 6, lane = threadIdx.x & 63;
    int v = blockIdx.x * 4 + w;
    if (v >= nNodes) return;
    xsh[w][lane] = xm[((size_t)v << 6) + lane];
    int s0 = start[v], s1 = start[v + 1];
    float acc = 0.0f;
    int p = s0;
    for (; p + 1 < s1; p += 2) {
        int e0 = eidx[p], e1 = eidx[p + 1];
        acc += msg[((size_t)e0 << 6) + lane] + msg[((size_t)e1 << 6) + lane];
    }
    if (p < s1) acc += msg[((size_t)eidx[p] << 6) + lane];
    acc /= fmaxf((float)(s1 - s0), 1.0f);
    float r = 0.0f;
    #pragma unroll 8
    for (int i = 0; i < 64; i++)
        r = fmaf(xsh[w][i], root[(i << 6) + lane], r);
    float val = eluf(acc + r + bias[lane]);
    atomicMax(&xmOut[((size_t)cl[v] << 6) + lane], f2sort(val));
}

// dst-CSR gather + fused node update + fused pool scatter, COUT=128.
__global__ __launch_bounds__(256) void conv_gather128(
    const float* __restrict__ msg, const int* __restrict__ start,
    const int* __restrict__ eidx, const float* __restrict__ xm,
    const float* __restrict__ root, const float* __restrict__ bias,
    const int* __restrict__ cl, unsigned* __restrict__ xmOut, int nNodes) {
    __shared__ float xsh[4][64];
    int w = threadIdx.x >> 6, lane = threadIdx.x & 63;
    int v = blockIdx.x * 4 + w;
    if (v >= nNodes) return;
    xsh[w][lane] = xm[((size_t)v << 6) + lane];
    int s0 = start[v], s1 = start[v + 1];
    float acc0 = 0.0f, acc1 = 0.0f;
    for (int p = s0; p < s1; p++) {
        const float* mrow = msg + ((size_t)eidx[p] << 7);
        acc0 += mrow[lane];
        acc1 += mrow[lane + 64];
    }
    float dinv = 1.0f / fmaxf((float)(s1 - s0), 1.0f);
    acc0 *= dinv; acc1 *= dinv;
    float r0 = 0.0f, r1 = 0.0f;
    #pragma unroll 8
    for (int i = 0; i < 64; i++) {
        float xi = xsh[w][i];
        r0 = fmaf(xi, root[(i << 7) + lane], r0);
        r1 = fmaf(xi, root[(i << 7) + 64 + lane], r1);
    }
    unsigned* orow = xmOut + ((size_t)cl[v] << 7);
    atomicMax(&orow[lane], f2sort(eluf(acc0 + r0 + bias[lane])));
    atomicMax(&orow[64 + lane], f2sort(eluf(acc1 + r1 + bias[lane + 64])));
}

// fused FC head: elu(x@fc1+b1) @ fc2 + b2, then log_softmax. One block per row.
__global__ __launch_bounds__(256) void fc_fused(
    const float* __restrict__ xin,
    const float* __restrict__ w1, const float* __restrict__ b1,
    const float* __restrict__ w2, const float* __restrict__ b2,
    float* __restrict__ out) {
    __shared__ float xsh[1024];
    __shared__ float hs[256];
    __shared__ float lg[10];
    int row = blockIdx.x;
    int o = threadIdx.x;
    for (int i = o; i < 1024; i += 256) xsh[i] = xin[row * 1024 + i];
    __syncthreads();
    float acc = b1[o];
    #pragma unroll 8
    for (int i = 0; i < 1024; i++) acc = fmaf(xsh[i], w1[i * 256 + o], acc);
    hs[o] = eluf(acc);
    __syncthreads();
    if (o < 10) {
        float a = b2[o];
        for (int i = 0; i < 256; i++) a = fmaf(hs[i], w2[i * 10 + o], a);
        lg[o] = a;
    }
    __syncthreads();
    if (o < 10) {
        float m = -1e30f;
        #pragma unroll
        for (int j = 0; j < 10; j++) m = fmaxf(m, lg[j]);
        float sum = 0.0f;
        #pragma unroll
        for (int j = 0; j < 10; j++) sum += expf(lg[j] - m);
        out[row * 10 + o] = lg[o] - m - logf(sum);
    }
}

extern "C" void kernel_launch(void* const* d_in, const int* in_sizes, int n_in,
                              void* d_out, int out_size, void* d_ws, size_t ws_size,
                              hipStream_t stream) {
    const float* x0      = (const float*)d_in[0];
    const int*   cluster0= (const int*)d_in[1];
    const int*   edge1   = (const int*)d_in[2];
    const float* pseudo1 = (const float*)d_in[3];
    const float* W1      = (const float*)d_in[4];
    const float* root1   = (const float*)d_in[5];
    const float* b1      = (const float*)d_in[6];
    const int*   cluster1= (const int*)d_in[7];
    const int*   edge2   = (const int*)d_in[8];
    const float* pseudo2 = (const float*)d_in[9];
    const float* W2      = (const float*)d_in[10];
    const float* root2   = (const float*)d_in[11];
    const float* b2      = (const float*)d_in[12];
    const int*   cluster2= (const int*)d_in[13];
    const int*   edge3   = (const int*)d_in[14];
    const float* pseudo3 = (const float*)d_in[15];
    const float* W3      = (const float*)d_in[16];
    const float* root3   = (const float*)d_in[17];
    const float* b3      = (const float*)d_in[18];
    const int*   cluster3= (const int*)d_in[19];
    const float* fc1_w   = (const float*)d_in[20];
    const float* fc1_b   = (const float*)d_in[21];
    const float* fc2_w   = (const float*)d_in[22];
    const float* fc2_b   = (const float*)d_in[23];
    float* out = (float*)d_out;

    float* ws = (float*)d_ws;
    size_t off = 0;
    // ---- zeroed region ----
    float* xm1  = ws + off; off += 20480;
    float* xm2  = ws + off; off += (size_t)N2c * 64;
    float* xm3  = ws + off; off += (size_t)N3c * 64;
    float* xm4  = ws + off; off += 512 * 128;
    int* cntD2   = (int*)(ws + off); off += 6016;
    int* curD2   = (int*)(ws + off); off += 6016;
    int* cntD3   = (int*)(ws + off); off += 1664;
    int* curD3   = (int*)(ws + off); off += 1664;
    size_t zeroFloats = off;
    // ---- non-zeroed region (fully written before read every launch) ----
    int* cube2     = (int*)(ws + off); off += E2c;
    int* order2    = (int*)(ws + off); off += E2c;
    int* cube3     = (int*)(ws + off); off += E3c;
    int* order3    = (int*)(ws + off); off += E3c;
    int* eidx2     = (int*)(ws + off); off += E2c;
    int* start2    = (int*)(ws + off); off += 6017;
    int* eidx3     = (int*)(ws + off); off += E3c;
    int* start3    = (int*)(ws + off); off += 1665;
    int* start1    = (int*)(ws + off); off += 1280;
    int* tot1      = (int*)(ws + off); off += 1280;
    int* blockCnt1 = (int*)(ws + off); off += HB1 * 1250;
    int* blockOff1 = (int*)(ws + off); off += HB1 * 1250;
    int* blockCnt2 = (int*)(ws + off); off += HB2 * 64;
    int* blockOff2 = (int*)(ws + off); off += HB2 * 64;
    int* blockCnt3 = (int*)(ws + off); off += HB3 * 64;
    int* blockOff3 = (int*)(ws + off); off += HB3 * 64;
    int* binCnt2   = (int*)(ws + off); off += 64;
    int* binStart2 = (int*)(ws + off); off += 64;
    int* blkPrefix2= (int*)(ws + off); off += 80;
    int* chunkBin2 = (int*)(ws + off); off += 1216;
    int* chunkOff2 = (int*)(ws + off); off += 1216;
    int* binCnt3   = (int*)(ws + off); off += 64;
    int* binStart3 = (int*)(ws + off); off += 64;
    int* blkPrefix3= (int*)(ws + off); off += 80;
    int* chunkBin3 = (int*)(ws + off); off += 384;
    int* chunkOff3 = (int*)(ws + off); off += 384;
    // big scratch: order1 (conv1) -> msg2 (conv2) -> msg3 (conv3), serially reused
    float* big  = ws + off; off += (size_t)E2c * 64;
    int*   order1 = (int*)big;
    float* msg2   = big;
    float* msg3   = big;

    hipMemsetAsync(d_ws, 0, zeroFloats * sizeof(float), stream);

    // pool 0: x0 -> xm1 (N1 x 1)
    segmax_scatter<<<(N0c + 255) / 256, 256, 0, stream>>>(x0, cluster0, (unsigned*)xm1, N0c, 0);
    segmax_decode<<<(N1c + 255) / 256, 256, 0, stream>>>((unsigned*)xm1, N1c);

    // conv1 (1 -> 64): LDS counting sort by dst>>4, per-16-node LDS accumulation,
    // epilogue scatters straight into pooled xm2 (sortable-uint atomicMax).
    key_hist_lds<<<HB1, 256, 0, stream>>>(edge1, E1c, blockCnt1);
    tot_k<<<5, 256, 0, stream>>>(blockCnt1, 1250, HB1, tot1);
    scan_excl<<<1, 256, 0, stream>>>(tot1, start1, 1250);
    off_k<<<5, 256, 0, stream>>>(blockCnt1, start1, 1250, HB1, blockOff1);
    key_scatter_lds<<<HB1, 256, 0, stream>>>(edge1, E1c, blockOff1, order1);
    conv1_block<<<1250, 256, 0, stream>>>(edge1, pseudo1, xm1, start1, order1,
                                          W1, root1, b1, cluster1, (unsigned*)xm2);
    segmax_decode<<<(N2c * 64) / 256, 256, 0, stream>>>((unsigned*)xm2, N2c * 64);

    // conv2 (64 -> 64): LDS cube sort -> independent-wave GEMM -> msg -> gather(+pool)
    bin_hist_v2<<<HB2, 256, 0, stream>>>(edge2, E2c, pseudo2, cube2, blockCnt2, cntD2, HB2);
    bin_plan_v2<<<1, 64, 0, stream>>>(blockCnt2, HB2, binCnt2, binStart2, blockOff2,
                                      blkPrefix2, chunkBin2, chunkOff2);
    bin_scatter_v2<<<HB2, 256, 0, stream>>>(cube2, E2c, blockOff2, order2, HB2);
    scan_excl<<<1, 256, 0, stream>>>(cntD2, start2, N2c);
    key_scatter<<<(E2c + 255) / 256, 256, 0, stream>>>(edge2, E2c, start2, curD2, eidx2);
    {
        int maxBlk = (E2c + 127) / 128 + 64;
        spline_gemm<64><<<dim3(maxBlk, 1), 256, 0, stream>>>(
            edge2, E2c, pseudo2, W2, xm2, order2, binStart2, binCnt2, blkPrefix2,
            chunkBin2, chunkOff2, msg2);
    }
    conv_gather64<<<(N2c + 3) / 4, 256, 0, stream>>>(msg2, start2, eidx2, xm2,
                                                     root2, b2, cluster2,
                                                     (unsigned*)xm3, N2c);
    segmax_decode<<<(N3c * 64) / 256, 256, 0, stream>>>((unsigned*)xm3, N3c * 64);

    // conv3 (64 -> 128): same pipeline, gather pools into xm4
    bin_hist_v2<<<HB3, 256, 0, stream>>>(edge3, E3c, pseudo3, cube3, blockCnt3, cntD3, HB3);
    bin_plan_v2<<<1, 64, 0, stream>>>(blockCnt3, HB3, binCnt3, binStart3, blockOff3,
                                      blkPrefix3, chunkBin3, chunkOff3);
    bin_scatter_v2<<<HB3, 256, 0, stream>>>(cube3, E3c, blockOff3, order3, HB3);
    scan_excl<<<1, 256, 0, stream>>>(cntD3, start3, N3c);
    key_scatter<<<(E3c + 255) / 256, 256, 0, stream>>>(edge3, E3c, start3, curD3, eidx3);
    {
        int maxBlk = (E3c + 127) / 128 + 64;
        spline_gemm<128><<<dim3(maxBlk, 2), 256, 0, stream>>>(
            edge3, E3c, pseudo3, W3, xm3, order3, binStart3, binCnt3, blkPrefix3,
            chunkBin3, chunkOff3, msg3);
    }
    conv_gather128<<<(N3c + 3) / 4, 256, 0, stream>>>(msg3, start3, eidx3, xm3,
                                                      root3, b3, cluster3,
                                                      (unsigned*)xm4, N3c);
    segmax_decode<<<(512 * 128) / 256, 256, 0, stream>>>((unsigned*)xm4, 512 * 128);

    // FC head (fused fc1+elu+fc2+log_softmax)
    fc_fused<<<64, 256, 0, stream>>>(xm4, fc1_w, fc1_b, fc2_w, fc2_b, out);
}

// Round 8
// 543.567 us; speedup vs baseline: 2.5721x; 1.2345x over previous
//
#include <hip/hip_runtime.h>
#include <hip/hip_bf16.h>
#include <math.h>

#define N0c 120000
#define N1c 20000
#define N2c 6000
#define N3c 1600
#define Bc  64
#define E1c 480000
#define E2c 144000
#define E3c 38400

#define HB1 128   // hist blocks for conv1 (1250 bins of dst>>4)
#define HB2 120   // hist blocks for conv2 cube sort
#define HB3 40    // hist blocks for conv3 cube sort

typedef __attribute__((ext_vector_type(8))) short short8;
typedef __attribute__((ext_vector_type(4))) float f32x4;

__device__ __forceinline__ float eluf(float x) {
    return x > 0.0f ? x : expm1f(x);
}

// monotone float -> uint mapping for atomicMax-based segment max
__device__ __forceinline__ unsigned f2sort(float f) {
    unsigned u = __float_as_uint(f);
    return (u & 0x80000000u) ? ~u : (u | 0x80000000u);
}
__device__ __forceinline__ float sort2f(unsigned u) {
    unsigned bits = (u & 0x80000000u) ? (u & 0x7FFFFFFFu) : ~u;
    return __uint_as_float(bits);
}

__device__ __forceinline__ unsigned short f2bf(float v) {
    unsigned u = __float_as_uint(v);
    unsigned r = (u + 0x7FFFu + ((u >> 16) & 1u)) >> 16;   // RNE
    return (unsigned short)r;
}

__global__ void segmax_scatter(const float* __restrict__ x, const int* __restrict__ cl,
                               unsigned* __restrict__ buf, int total, int shiftC) {
    int idx = blockIdx.x * blockDim.x + threadIdx.x;
    if (idx >= total) return;
    int n = idx >> shiftC;
    int c = idx - (n << shiftC);
    atomicMax(&buf[(cl[n] << shiftC) + c], f2sort(x[idx]));
}

__global__ void segmax_decode(unsigned* __restrict__ buf, int total) {
    int idx = blockIdx.x * blockDim.x + threadIdx.x;
    if (idx >= total) return;
    float f = sort2f(buf[idx]);
    unsigned b = __float_as_uint(f);
    if ((b & 0x7F800000u) == 0x7F800000u) f = 0.0f;   // !isfinite -> 0
    ((float*)buf)[idx] = f;
}

// convert node features fp32 -> bf16 (same layout)
__global__ void cvt_x(const float* __restrict__ x, unsigned short* __restrict__ xb,
                      int total) {
    int idx = blockIdx.x * blockDim.x + threadIdx.x;
    if (idx >= total) return;
    xb[idx] = f2bf(x[idx]);
}

// convert W[k][ic][cout] fp32 -> Wt[k][n][ic] bf16 (transposed, CIN=64)
__global__ void cvt_w(const float* __restrict__ W, unsigned short* __restrict__ Wt,
                      int K, int COUT) {
    int idx = blockIdx.x * blockDim.x + threadIdx.x;
    int total = K * COUT * 64;
    if (idx >= total) return;
    int ic = idx & 63;
    int kn = idx >> 6;
    int n = kn % COUT;
    int k = kn / COUT;
    Wt[idx] = f2bf(W[((size_t)k * 64 + ic) * COUT + n]);
}

// single-block exclusive scan, items-per-thread + one LDS scan
__global__ __launch_bounds__(256) void scan_excl(const int* __restrict__ cnt,
                                                 int* __restrict__ start, int n) {
    __shared__ int ps[256];
    int t = threadIdx.x;
    int items = (n + 255) >> 8;
    int base = t * items;
    int s = 0;
    for (int i = 0; i < items; i++) {
        int idx = base + i;
        if (idx < n) s += cnt[idx];
    }
    ps[t] = s;
    __syncthreads();
    for (int ofs = 1; ofs < 256; ofs <<= 1) {
        int add = (t >= ofs) ? ps[t - ofs] : 0;
        __syncthreads();
        ps[t] += add;
        __syncthreads();
    }
    int run = (t == 0) ? 0 : ps[t - 1];
    for (int i = 0; i < items; i++) {
        int idx = base + i;
        if (idx < n) { start[idx] = run; run += cnt[idx]; }
    }
    if (t == 255) start[n] = run;
}

// dst-CSR scatter (uncontended: ~24 edges per dst)
__global__ void key_scatter(const int* __restrict__ edge, int E,
                            const int* __restrict__ start, int* __restrict__ cursor,
                            int* __restrict__ ord) {
    int e = blockIdx.x * blockDim.x + threadIdx.x;
    if (e >= E) return;
    int d = edge[E + e];
    int p = atomicAdd(&cursor[d], 1);
    ord[start[d] + p] = e;
}

// ---- conv1 counting sort by dst>>4 (1250 bins), LDS-aggregated ----

__global__ __launch_bounds__(256) void key_hist_lds(const int* __restrict__ edge, int E,
                                                    int* __restrict__ blockCnt) {
    __shared__ int h[1250];
    for (int i = threadIdx.x; i < 1250; i += 256) h[i] = 0;
    __syncthreads();
    for (int e = blockIdx.x * 256 + threadIdx.x; e < E; e += HB1 * 256)
        atomicAdd(&h[edge[E + e] >> 4], 1);
    __syncthreads();
    for (int i = threadIdx.x; i < 1250; i += 256)
        blockCnt[blockIdx.x * 1250 + i] = h[i];
}

__global__ void tot_k(const int* __restrict__ blockCnt, int nbins, int nblk,
                      int* __restrict__ tot) {
    int i = blockIdx.x * blockDim.x + threadIdx.x;
    if (i >= nbins) return;
    int s = 0;
    for (int b = 0; b < nblk; b++) s += blockCnt[b * nbins + i];
    tot[i] = s;
}

__global__ void off_k(const int* __restrict__ blockCnt, const int* __restrict__ binStart,
                      int nbins, int nblk, int* __restrict__ blockOff) {
    int i = blockIdx.x * blockDim.x + threadIdx.x;
    if (i >= nbins) return;
    int run = binStart[i];
    for (int b = 0; b < nblk; b++) {
        blockOff[b * nbins + i] = run;
        run += blockCnt[b * nbins + i];
    }
}

__global__ __launch_bounds__(256) void key_scatter_lds(const int* __restrict__ edge, int E,
                                                       const int* __restrict__ blockOff,
                                                       int* __restrict__ order) {
    __shared__ int cur[1250];
    for (int i = threadIdx.x; i < 1250; i += 256)
        cur[i] = blockOff[blockIdx.x * 1250 + i];
    __syncthreads();
    for (int e = blockIdx.x * 256 + threadIdx.x; e < E; e += HB1 * 256) {
        int p = atomicAdd(&cur[edge[E + e] >> 4], 1);
        order[p] = e;
    }
}

// ---- conv1 (C_in=1): per-16-node block, LDS knot accumulation + tiny GEMM ----
// Epilogue fused with pool1: atomicMax into xm2 (sortable-uint).
__global__ __launch_bounds__(256) void conv1_block(
    const int* __restrict__ edge, const float* __restrict__ pseudo,
    const float* __restrict__ x,
    const int* __restrict__ start, const int* __restrict__ order,
    const float* __restrict__ W, const float* __restrict__ root,
    const float* __restrict__ bias, const int* __restrict__ cl,
    unsigned* __restrict__ xmOut) {
    __shared__ float T[16][128];
    __shared__ int degL[16];
    int b = blockIdx.x;
    for (int j = threadIdx.x; j < 2048; j += 256) ((float*)T)[j] = 0.0f;
    if (threadIdx.x < 16) degL[threadIdx.x] = 0;
    __syncthreads();
    int s0 = start[b], s1 = start[b + 1];
    for (int i = s0 + threadIdx.x; i < s1; i += 256) {
        int e = order[i];
        int src = edge[e], dst = edge[E1c + e];
        int ln = dst & 15;
        float xv = x[src];
        float f[3];
        int loi[3];
        #pragma unroll
        for (int d = 0; d < 3; d++) {
            float pp = pseudo[e * 3 + d] * 4.0f;
            float l = fminf(fmaxf(floorf(pp), 0.0f), 3.0f);
            f[d] = pp - l;
            loi[d] = (int)l;
        }
        int kbase = loi[0] + 5 * loi[1] + 25 * loi[2];
        #pragma unroll
        for (int s = 0; s < 8; s++) {
            int b0 = s & 1, b1 = (s >> 1) & 1, b2 = (s >> 2) & 1;
            float w0 = b0 ? f[0] : 1.0f - f[0];
            float w1 = b1 ? f[1] : 1.0f - f[1];
            float w2 = b2 ? f[2] : 1.0f - f[2];
            int k = kbase + b0 + 5 * b1 + 25 * b2;
            atomicAdd(&T[ln][k], xv * w0 * w1 * w2);
        }
        atomicAdd(&degL[ln], 1);
    }
    __syncthreads();
    int w = threadIdx.x >> 6, lane = threadIdx.x & 63;
    float acc[4] = {0.0f, 0.0f, 0.0f, 0.0f};
    for (int k = 0; k < 125; k++) {
        float wv = W[(k << 6) + lane];
        #pragma unroll
        for (int j = 0; j < 4; j++)
            acc[j] = fmaf(T[w + 4 * j][k], wv, acc[j]);
    }
    int v0 = b << 4;
    #pragma unroll
    for (int j = 0; j < 4; j++) {
        int ln = w + 4 * j;
        int v = v0 + ln;
        float d = fmaxf((float)degL[ln], 1.0f);
        float val = eluf(acc[j] / d + x[v] * root[lane] + bias[lane]);
        atomicMax(&xmOut[((size_t)cl[v] << 6) + lane], f2sort(val));
    }
}

// ---- conv2/conv3 counting sort by spline cube (64 bins), LDS-aggregated ----

__global__ __launch_bounds__(256) void bin_hist_v2(const int* __restrict__ edge, int E,
                                                   const float* __restrict__ pseudo,
                                                   int* __restrict__ cube,
                                                   int* __restrict__ blockCnt,
                                                   int* __restrict__ dstCnt, int nblk) {
    __shared__ int h[64];
    int t = threadIdx.x;
    if (t < 64) h[t] = 0;
    __syncthreads();
    for (int e = blockIdx.x * 256 + t; e < E; e += nblk * 256) {
        int c = 0, mul = 1;
        #pragma unroll
        for (int d = 0; d < 3; d++) {
            float p = pseudo[e * 3 + d] * 4.0f;
            float l = fminf(fmaxf(floorf(p), 0.0f), 3.0f);
            c += (int)l * mul;
            mul <<= 2;
        }
        cube[e] = c;
        atomicAdd(&h[c], 1);
        atomicAdd(&dstCnt[edge[E + e]], 1);
    }
    __syncthreads();
    if (t < 64) blockCnt[blockIdx.x * 64 + t] = h[t];
}

// one block, 64 threads: totals, bin starts, per-(block,bin) offsets, chunk map
// Chunk granularity = 32 edges (one MFMA wave).
__global__ void bin_plan_v2(const int* __restrict__ blockCnt, int nblk,
                            int* __restrict__ binCnt, int* __restrict__ binStart,
                            int* __restrict__ blockOff, int* __restrict__ blkPrefix,
                            int* __restrict__ chunkBin, int* __restrict__ chunkOff) {
    __shared__ int tot[64], ss[64], ps[64];
    int t = threadIdx.x;
    int sum = 0;
    for (int b = 0; b < nblk; b++) sum += blockCnt[b * 64 + t];
    tot[t] = sum;
    __syncthreads();
    if (t == 0) {
        int s = 0, p = 0;
        for (int c = 0; c < 64; c++) {
            ss[c] = s; ps[c] = p;
            s += tot[c];
            p += (tot[c] + 31) >> 5;
        }
        blkPrefix[64] = p;
    }
    __syncthreads();
    binCnt[t] = tot[t];
    binStart[t] = ss[t];
    blkPrefix[t] = ps[t];
    int run = ss[t];
    for (int b = 0; b < nblk; b++) {
        blockOff[b * 64 + t] = run;
        run += blockCnt[b * 64 + t];
    }
    int nch = (tot[t] + 31) >> 5;
    for (int j = 0; j < nch; j++) {
        chunkBin[ps[t] + j] = t;
        chunkOff[ps[t] + j] = j;
    }
}

__global__ __launch_bounds__(256) void bin_scatter_v2(const int* __restrict__ cube, int E,
                                                      const int* __restrict__ blockOff,
                                                      int* __restrict__ order, int nblk) {
    __shared__ int cur[64];
    int t = threadIdx.x;
    if (t < 64) cur[t] = blockOff[blockIdx.x * 64 + t];
    __syncthreads();
    for (int e = blockIdx.x * 256 + t; e < E; e += nblk * 256) {
        int p = atomicAdd(&cur[cube[e]], 1);
        order[p] = e;
    }
}

// Binned spline-conv via bf16 MFMA (fp32 accumulate), fully independent waves.
// Wave = one chunk of 32 edges x 64 out-cols: 2 row-tiles x 4 N-tiles of
// 16x16x32 MFMA. A-frags (pure x, bf16) in registers, reused over all 8 taps.
// B-frags loaded straight from L2 (Wt[k][n][ic] bf16). Per-tap C scaled by
// basis (fp32) into running acc. Epilogue: LDS transpose -> coalesced msg.
template<int COUT>
__global__ __launch_bounds__(256) void spline_mfma(
    const int* __restrict__ edge, int E,
    const float* __restrict__ pseudo,
    const unsigned short* __restrict__ Wt,
    const unsigned short* __restrict__ xb,
    const int* __restrict__ order,
    const int* __restrict__ binStart,
    const int* __restrict__ binCnt,
    const int* __restrict__ blkPrefix,
    const int* __restrict__ chunkBin,
    const int* __restrict__ chunkOff,
    float* __restrict__ msg)
{
    __shared__ float basisS[4][8][32];
    __shared__ int srcS[4][32];
    __shared__ int eS[4][32];
    __shared__ float buf[4][16][68];   // stride 68: 16B-aligned rows, 2-way banks

    int w = threadIdx.x >> 6, lane = threadIdx.x & 63;
    int c = blockIdx.x * 4 + w;
    if (c >= blkPrefix[64]) return;
    int bin = chunkBin[c];
    int chunk = chunkOff[c];
    int cnt = binCnt[bin];

    // setup by lanes 0..31 (one per edge)
    if (lane < 32) {
        int pos = chunk * 32 + lane;
        bool act = pos < cnt;
        int e = act ? order[binStart[bin] + pos] : 0;
        eS[w][lane] = e;
        srcS[w][lane] = act ? edge[e] : 0;
        float f0 = 0.0f, f1 = 0.0f, f2 = 0.0f;
        if (act) {
            float p0 = pseudo[e * 3 + 0] * 4.0f;
            float p1 = pseudo[e * 3 + 1] * 4.0f;
            float p2 = pseudo[e * 3 + 2] * 4.0f;
            f0 = p0 - fminf(fmaxf(floorf(p0), 0.0f), 3.0f);
            f1 = p1 - fminf(fmaxf(floorf(p1), 0.0f), 3.0f);
            f2 = p2 - fminf(fmaxf(floorf(p2), 0.0f), 3.0f);
        }
        #pragma unroll
        for (int s = 0; s < 8; s++) {
            float w0 = (s & 1) ? f0 : 1.0f - f0;
            float w1 = (s & 2) ? f1 : 1.0f - f1;
            float w2 = (s & 4) ? f2 : 1.0f - f2;
            basisS[w][s][lane] = act ? (w0 * w1 * w2) : 0.0f;
        }
    }
    __builtin_amdgcn_wave_barrier();
    __threadfence_block();   // LDS writes visible to whole wave

    int lo0 = bin & 3, lo1 = (bin >> 2) & 3, lo2 = bin >> 4;
    int kbase = lo0 + 5 * lo1 + 25 * lo2;
    int colOff = (COUT == 128) ? (blockIdx.y << 6) : 0;
    int q = lane >> 4;        // quad
    int mcol = lane & 15;     // A row / B col / C col

    // A-frags: afr[rowtile][kchunk], element j = x_bf16[src(m)][ch*32 + q*8 + j]
    short8 afr[2][2];
    #pragma unroll
    for (int rt = 0; rt < 2; rt++) {
        int src = srcS[w][rt * 16 + mcol];
        const unsigned short* xr = xb + ((size_t)src << 6) + q * 8;
        afr[rt][0] = *(const short8*)(xr);
        afr[rt][1] = *(const short8*)(xr + 32);
    }

    f32x4 acc[2][4];
    #pragma unroll
    for (int rt = 0; rt < 2; rt++)
        #pragma unroll
        for (int nt = 0; nt < 4; nt++)
            acc[rt][nt] = (f32x4){0.0f, 0.0f, 0.0f, 0.0f};
    const f32x4 zero4 = {0.0f, 0.0f, 0.0f, 0.0f};

    #pragma unroll 1
    for (int s = 0; s < 8; s++) {
        int k = kbase + (s & 1) + 5 * ((s >> 1) & 1) + 25 * (s >> 2);
        const unsigned short* Wk = Wt + ((size_t)k * COUT + colOff) * 64;
        f32x4 ct[2][4];
        #pragma unroll
        for (int nt = 0; nt < 4; nt++) {
            const unsigned short* Wn = Wk + (size_t)(nt * 16 + mcol) * 64 + q * 8;
            short8 b0 = *(const short8*)(Wn);
            short8 b1 = *(const short8*)(Wn + 32);
            ct[0][nt] = __builtin_amdgcn_mfma_f32_16x16x32_bf16(afr[0][0], b0, zero4, 0, 0, 0);
            ct[0][nt] = __builtin_amdgcn_mfma_f32_16x16x32_bf16(afr[0][1], b1, ct[0][nt], 0, 0, 0);
            ct[1][nt] = __builtin_amdgcn_mfma_f32_16x16x32_bf16(afr[1][0], b0, zero4, 0, 0, 0);
            ct[1][nt] = __builtin_amdgcn_mfma_f32_16x16x32_bf16(afr[1][1], b1, ct[1][nt], 0, 0, 0);
        }
        // scale per-tap C by basis(row) into running acc (C/D row = q*4+reg)
        #pragma unroll
        for (int rt = 0; rt < 2; rt++)
            #pragma unroll
            for (int r = 0; r < 4; r++) {
                float bs = basisS[w][s][rt * 16 + q * 4 + r];
                #pragma unroll
                for (int nt = 0; nt < 4; nt++)
                    acc[rt][nt][r] = fmaf(bs, ct[rt][nt][r], acc[rt][nt][r]);
            }
    }

    // Epilogue: per row-tile, transpose through LDS, coalesced msg stores.
    int rowG = lane >> 2;            // 0..15
    int cg = (lane & 3) * 16;        // col group
    #pragma unroll 1
    for (int rt = 0; rt < 2; rt++) {
        __builtin_amdgcn_wave_barrier();
        #pragma unroll
        for (int nt = 0; nt < 4; nt++)
            #pragma unroll
            for (int r = 0; r < 4; r++)
                buf[w][q * 4 + r][nt * 16 + mcol] = acc[rt][nt][r];
        __builtin_amdgcn_wave_barrier();
        __threadfence_block();
        if (chunk * 32 + rt * 16 + rowG < cnt) {
            float* mrow = msg + (size_t)eS[w][rt * 16 + rowG] * COUT + colOff + cg;
            #pragma unroll
            for (int j = 0; j < 4; j++)
                *(float4*)(mrow + j * 4) = *(const float4*)(&buf[w][rowG][cg + j * 4]);
        }
        __builtin_amdgcn_wave_barrier();
    }
}

// dst-CSR gather + fused node update + fused pool scatter, COUT=64.
__global__ __launch_bounds__(256) void conv_gather64(
    const float* __restrict__ msg, const int* __restrict__ start,
    const int* __restrict__ eidx, const float* __restrict__ xm,
    const float* __restrict__ root, const float* __restrict__ bias,
    const int* __restrict__ cl, unsigned* __restrict__ xmOut, int nNodes) {
    __shared__ float xsh[4][64];
    int w = threadIdx.x >> 6, lane = threadIdx.x & 63;
    int v = blockIdx.x * 4 + w;
    if (v >= nNodes) return;
    xsh[w][lane] = xm[((size_t)v << 6) + lane];
    int s0 = start[v], s1 = start[v + 1];
    float acc = 0.0f;
    int p = s0;
    for (; p + 1 < s1; p += 2) {
        int e0 = eidx[p], e1 = eidx[p + 1];
        acc += msg[((size_t)e0 << 6) + lane] + msg[((size_t)e1 << 6) + lane];
    }
    if (p < s1) acc += msg[((size_t)eidx[p] << 6) + lane];
    acc /= fmaxf((float)(s1 - s0), 1.0f);
    float r = 0.0f;
    #pragma unroll 8
    for (int i = 0; i < 64; i++)
        r = fmaf(xsh[w][i], root[(i << 6) + lane], r);
    float val = eluf(acc + r + bias[lane]);
    atomicMax(&xmOut[((size_t)cl[v] << 6) + lane], f2sort(val));
}

// dst-CSR gather + fused node update + fused pool scatter, COUT=128.
__global__ __launch_bounds__(256) void conv_gather128(
    const float* __restrict__ msg, const int* __restrict__ start,
    const int* __restrict__ eidx, const float* __restrict__ xm,
    const float* __restrict__ root, const float* __restrict__ bias,
    const int* __restrict__ cl, unsigned* __restrict__ xmOut, int nNodes) {
    __shared__ float xsh[4][64];
    int w = threadIdx.x >> 6, lane = threadIdx.x & 63;
    int v = blockIdx.x * 4 + w;
    if (v >= nNodes) return;
    xsh[w][lane] = xm[((size_t)v << 6) + lane];
    int s0 = start[v], s1 = start[v + 1];
    float acc0 = 0.0f, acc1 = 0.0f;
    for (int p = s0; p < s1; p++) {
        const float* mrow = msg + ((size_t)eidx[p] << 7);
        acc0 += mrow[lane];
        acc1 += mrow[lane + 64];
    }
    float dinv = 1.0f / fmaxf((float)(s1 - s0), 1.0f);
    acc0 *= dinv; acc1 *= dinv;
    float r0 = 0.0f, r1 = 0.0f;
    #pragma unroll 8
    for (int i = 0; i < 64; i++) {
        float xi = xsh[w][i];
        r0 = fmaf(xi, root[(i << 7) + lane], r0);
        r1 = fmaf(xi, root[(i << 7) + 64 + lane], r1);
    }
    unsigned* orow = xmOut + ((size_t)cl[v] << 7);
    atomicMax(&orow[lane], f2sort(eluf(acc0 + r0 + bias[lane])));
    atomicMax(&orow[64 + lane], f2sort(eluf(acc1 + r1 + bias[lane + 64])));
}

// fused FC head: elu(x@fc1+b1) @ fc2 + b2, then log_softmax. One block per row.
__global__ __launch_bounds__(256) void fc_fused(
    const float* __restrict__ xin,
    const float* __restrict__ w1, const float* __restrict__ b1,
    const float* __restrict__ w2, const float* __restrict__ b2,
    float* __restrict__ out) {
    __shared__ float xsh[1024];
    __shared__ float hs[256];
    __shared__ float lg[10];
    int row = blockIdx.x;
    int o = threadIdx.x;
    for (int i = o; i < 1024; i += 256) xsh[i] = xin[row * 1024 + i];
    __syncthreads();
    float acc = b1[o];
    #pragma unroll 8
    for (int i = 0; i < 1024; i++) acc = fmaf(xsh[i], w1[i * 256 + o], acc);
    hs[o] = eluf(acc);
    __syncthreads();
    if (o < 10) {
        float a = b2[o];
        for (int i = 0; i < 256; i++) a = fmaf(hs[i], w2[i * 10 + o], a);
        lg[o] = a;
    }
    __syncthreads();
    if (o < 10) {
        float m = -1e30f;
        #pragma unroll
        for (int j = 0; j < 10; j++) m = fmaxf(m, lg[j]);
        float sum = 0.0f;
        #pragma unroll
        for (int j = 0; j < 10; j++) sum += expf(lg[j] - m);
        out[row * 10 + o] = lg[o] - m - logf(sum);
    }
}

extern "C" void kernel_launch(void* const* d_in, const int* in_sizes, int n_in,
                              void* d_out, int out_size, void* d_ws, size_t ws_size,
                              hipStream_t stream) {
    const float* x0      = (const float*)d_in[0];
    const int*   cluster0= (const int*)d_in[1];
    const int*   edge1   = (const int*)d_in[2];
    const float* pseudo1 = (const float*)d_in[3];
    const float* W1      = (const float*)d_in[4];
    const float* root1   = (const float*)d_in[5];
    const float* b1      = (const float*)d_in[6];
    const int*   cluster1= (const int*)d_in[7];
    const int*   edge2   = (const int*)d_in[8];
    const float* pseudo2 = (const float*)d_in[9];
    const float* W2      = (const float*)d_in[10];
    const float* root2   = (const float*)d_in[11];
    const float* b2      = (const float*)d_in[12];
    const int*   cluster2= (const int*)d_in[13];
    const int*   edge3   = (const int*)d_in[14];
    const float* pseudo3 = (const float*)d_in[15];
    const float* W3      = (const float*)d_in[16];
    const float* root3   = (const float*)d_in[17];
    const float* b3      = (const float*)d_in[18];
    const int*   cluster3= (const int*)d_in[19];
    const float* fc1_w   = (const float*)d_in[20];
    const float* fc1_b   = (const float*)d_in[21];
    const float* fc2_w   = (const float*)d_in[22];
    const float* fc2_b   = (const float*)d_in[23];
    float* out = (float*)d_out;

    float* ws = (float*)d_ws;
    size_t off = 0;
    // ---- zeroed region ----
    float* xm1  = ws + off; off += 20480;
    float* xm2  = ws + off; off += (size_t)N2c * 64;
    float* xm3  = ws + off; off += (size_t)N3c * 64;
    float* xm4  = ws + off; off += 512 * 128;
    int* cntD2   = (int*)(ws + off); off += 6016;
    int* curD2   = (int*)(ws + off); off += 6016;
    int* cntD3   = (int*)(ws + off); off += 1664;
    int* curD3   = (int*)(ws + off); off += 1664;
    size_t zeroFloats = off;
    // ---- non-zeroed region (fully written before read every launch) ----
    unsigned short* W2t = (unsigned short*)(ws + off); off += 125 * 64 * 64 / 2;
    unsigned short* W3t = (unsigned short*)(ws + off); off += 125 * 128 * 64 / 2;
    unsigned short* xb2 = (unsigned short*)(ws + off); off += (size_t)N2c * 64 / 2;
    unsigned short* xb3 = (unsigned short*)(ws + off); off += (size_t)N3c * 64 / 2;
    int* cube2     = (int*)(ws + off); off += E2c;
    int* order2    = (int*)(ws + off); off += E2c;
    int* cube3     = (int*)(ws + off); off += E3c;
    int* order3    = (int*)(ws + off); off += E3c;
    int* eidx2     = (int*)(ws + off); off += E2c;
    int* start2    = (int*)(ws + off); off += 6020;
    int* eidx3     = (int*)(ws + off); off += E3c;
    int* start3    = (int*)(ws + off); off += 1668;
    int* start1    = (int*)(ws + off); off += 1280;
    int* tot1      = (int*)(ws + off); off += 1280;
    int* blockCnt1 = (int*)(ws + off); off += HB1 * 1250;
    int* blockOff1 = (int*)(ws + off); off += HB1 * 1250;
    int* blockCnt2 = (int*)(ws + off); off += HB2 * 64;
    int* blockOff2 = (int*)(ws + off); off += HB2 * 64;
    int* blockCnt3 = (int*)(ws + off); off += HB3 * 64;
    int* blockOff3 = (int*)(ws + off); off += HB3 * 64;
    int* binCnt2   = (int*)(ws + off); off += 64;
    int* binStart2 = (int*)(ws + off); off += 64;
    int* blkPrefix2= (int*)(ws + off); off += 80;
    int* chunkBin2 = (int*)(ws + off); off += 4608;
    int* chunkOff2 = (int*)(ws + off); off += 4608;
    int* binCnt3   = (int*)(ws + off); off += 64;
    int* binStart3 = (int*)(ws + off); off += 64;
    int* blkPrefix3= (int*)(ws + off); off += 80;
    int* chunkBin3 = (int*)(ws + off); off += 1280;
    int* chunkOff3 = (int*)(ws + off); off += 1280;
    // big scratch: order1 (conv1) -> msg2 (conv2) -> msg3 (conv3), serially reused
    float* big  = ws + off; off += (size_t)E2c * 64;
    int*   order1 = (int*)big;
    float* msg2   = big;
    float* msg3   = big;

    hipMemsetAsync(d_ws, 0, zeroFloats * sizeof(float), stream);

    // weight conversions (independent of everything else)
    cvt_w<<<(125 * 64 * 64 + 255) / 256, 256, 0, stream>>>(W2, W2t, 125, 64);
    cvt_w<<<(125 * 128 * 64 + 255) / 256, 256, 0, stream>>>(W3, W3t, 125, 128);

    // pool 0: x0 -> xm1 (N1 x 1)
    segmax_scatter<<<(N0c + 255) / 256, 256, 0, stream>>>(x0, cluster0, (unsigned*)xm1, N0c, 0);
    segmax_decode<<<(N1c + 255) / 256, 256, 0, stream>>>((unsigned*)xm1, N1c);

    // conv1 (1 -> 64): LDS counting sort by dst>>4, per-16-node LDS accumulation,
    // epilogue scatters straight into pooled xm2 (sortable-uint atomicMax).
    key_hist_lds<<<HB1, 256, 0, stream>>>(edge1, E1c, blockCnt1);
    tot_k<<<5, 256, 0, stream>>>(blockCnt1, 1250, HB1, tot1);
    scan_excl<<<1, 256, 0, stream>>>(tot1, start1, 1250);
    off_k<<<5, 256, 0, stream>>>(blockCnt1, start1, 1250, HB1, blockOff1);
    key_scatter_lds<<<HB1, 256, 0, stream>>>(edge1, E1c, blockOff1, order1);
    conv1_block<<<1250, 256, 0, stream>>>(edge1, pseudo1, xm1, start1, order1,
                                          W1, root1, b1, cluster1, (unsigned*)xm2);
    segmax_decode<<<(N2c * 64) / 256, 256, 0, stream>>>((unsigned*)xm2, N2c * 64);
    cvt_x<<<(N2c * 64 + 255) / 256, 256, 0, stream>>>(xm2, xb2, N2c * 64);

    // conv2 (64 -> 64): LDS cube sort -> MFMA GEMM -> msg -> gather(+pool)
    bin_hist_v2<<<HB2, 256, 0, stream>>>(edge2, E2c, pseudo2, cube2, blockCnt2, cntD2, HB2);
    bin_plan_v2<<<1, 64, 0, stream>>>(blockCnt2, HB2, binCnt2, binStart2, blockOff2,
                                      blkPrefix2, chunkBin2, chunkOff2);
    bin_scatter_v2<<<HB2, 256, 0, stream>>>(cube2, E2c, blockOff2, order2, HB2);
    scan_excl<<<1, 256, 0, stream>>>(cntD2, start2, N2c);
    key_scatter<<<(E2c + 255) / 256, 256, 0, stream>>>(edge2, E2c, start2, curD2, eidx2);
    {
        int maxChunk = E2c / 32 + 64;
        spline_mfma<64><<<dim3((maxChunk + 3) / 4, 1), 256, 0, stream>>>(
            edge2, E2c, pseudo2, W2t, xb2, order2, binStart2, binCnt2, blkPrefix2,
            chunkBin2, chunkOff2, msg2);
    }
    conv_gather64<<<(N2c + 3) / 4, 256, 0, stream>>>(msg2, start2, eidx2, xm2,
                                                     root2, b2, cluster2,
                                                     (unsigned*)xm3, N2c);
    segmax_decode<<<(N3c * 64) / 256, 256, 0, stream>>>((unsigned*)xm3, N3c * 64);
    cvt_x<<<(N3c * 64 + 255) / 256, 256, 0, stream>>>(xm3, xb3, N3c * 64);

    // conv3 (64 -> 128): same pipeline, gather pools into xm4
    bin_hist_v2<<<HB3, 256, 0, stream>>>(edge3, E3c, pseudo3, cube3, blockCnt3, cntD3, HB3);
    bin_plan_v2<<<1, 64, 0, stream>>>(blockCnt3, HB3, binCnt3, binStart3, blockOff3,
                                      blkPrefix3, chunkBin3, chunkOff3);
    bin_scatter_v2<<<HB3, 256, 0, stream>>>(cube3, E3c, blockOff3, order3, HB3);
    scan_excl<<<1, 256, 0, stream>>>(cntD3, start3, N3c);
    key_scatter<<<(E3c + 255) / 256, 256, 0, stream>>>(edge3, E3c, start3, curD3, eidx3);
    {
        int maxChunk = E3c / 32 + 64;
        spline_mfma<128><<<dim3((maxChunk + 3) / 4, 2), 256, 0, stream>>>(
            edge3, E3c, pseudo3, W3t, xb3, order3, binStart3, binCnt3, blkPrefix3,
            chunkBin3, chunkOff3, msg3);
    }
    conv_gather128<<<(N3c + 3) / 4, 256, 0, stream>>>(msg3, start3, eidx3, xm3,
                                                      root3, b3, cluster3,
                                                      (unsigned*)xm4, N3c);
    segmax_decode<<<(512 * 128) / 256, 256, 0, stream>>>((unsigned*)xm4, 512 * 128);

    // FC head (fused fc1+elu+fc2+log_softmax)
    fc_fused<<<64, 256, 0, stream>>>(xm4, fc1_w, fc1_b, fc2_w, fc2_b, out);
}

// Round 9
// 408.607 us; speedup vs baseline: 3.4217x; 1.3303x over previous
//
#include <hip/hip_runtime.h>
#include <hip/hip_bf16.h>
#include <math.h>

#define N0c 120000
#define N1c 20000
#define N2c 6000
#define N3c 1600
#define E1c 480000
#define E2c 144000
#define E3c 38400

#define HB1 32    // hist/scatter blocks for conv1 (1250 bins of dst>>4)
#define HB2 120   // hist/scatter blocks for conv2 cube sort
#define HB3 40    // hist/scatter blocks for conv3 cube sort
#define CVT2B 2000  // 125*64*64/256
#define CVT3B 4000  // 125*128*64/256
#define SS0B  469   // (120000+255)/256

typedef __attribute__((ext_vector_type(8))) short short8;
typedef __attribute__((ext_vector_type(4))) float f32x4;

__device__ __forceinline__ float eluf(float x) {
    return x > 0.0f ? x : expm1f(x);
}

__device__ __forceinline__ unsigned f2sort(float f) {
    unsigned u = __float_as_uint(f);
    return (u & 0x80000000u) ? ~u : (u | 0x80000000u);
}
__device__ __forceinline__ float sort2f(unsigned u) {
    unsigned bits = (u & 0x80000000u) ? (u & 0x7FFFFFFFu) : ~u;
    return __uint_as_float(bits);
}
__device__ __forceinline__ unsigned short f2bf(float v) {
    unsigned u = __float_as_uint(v);
    unsigned r = (u + 0x7FFFu + ((u >> 16) & 1u)) >> 16;   // RNE
    return (unsigned short)r;
}

// ---- STAGE A: all feature-independent prep, one kernel, blockIdx ranges ----
// [0,HB1): conv1 1250-bin LDS hist  [HB1,+HB2): conv2 cube+hist+dstdeg
// [+,HB3): conv3 same  [+,CVT2B): W2->bf16^T  [+,CVT3B): W3->bf16^T
// [+,SS0B): pool0 scatter (x0 -> xm1 atomicMax)
__global__ __launch_bounds__(256) void hist_all(
    const int* __restrict__ edge1, const int* __restrict__ edge2,
    const int* __restrict__ edge3,
    const float* __restrict__ pseudo2, const float* __restrict__ pseudo3,
    const float* __restrict__ W2, const float* __restrict__ W3,
    const float* __restrict__ x0, const int* __restrict__ cluster0,
    int* __restrict__ blockCnt1,
    int* __restrict__ cube2, int* __restrict__ blockCnt2, int* __restrict__ cntD2,
    int* __restrict__ cube3, int* __restrict__ blockCnt3, int* __restrict__ cntD3,
    unsigned short* __restrict__ W2t, unsigned short* __restrict__ W3t,
    unsigned* __restrict__ xm1)
{
    __shared__ int h[1250];
    int b = blockIdx.x, t = threadIdx.x;
    if (b < HB1) {
        for (int i = t; i < 1250; i += 256) h[i] = 0;
        __syncthreads();
        for (int e = b * 256 + t; e < E1c; e += HB1 * 256)
            atomicAdd(&h[edge1[E1c + e] >> 4], 1);
        __syncthreads();
        for (int i = t; i < 1250; i += 256) blockCnt1[b * 1250 + i] = h[i];
    } else if (b < HB1 + HB2 + HB3) {
        bool is2 = b < HB1 + HB2;
        int rb = is2 ? (b - HB1) : (b - HB1 - HB2);
        int nblk = is2 ? HB2 : HB3;
        int E = is2 ? E2c : E3c;
        const int* edge = is2 ? edge2 : edge3;
        const float* pseudo = is2 ? pseudo2 : pseudo3;
        int* cube = is2 ? cube2 : cube3;
        int* blockCnt = is2 ? blockCnt2 : blockCnt3;
        int* dstCnt = is2 ? cntD2 : cntD3;
        if (t < 64) h[t] = 0;
        __syncthreads();
        for (int e = rb * 256 + t; e < E; e += nblk * 256) {
            int c = 0, mul = 1;
            #pragma unroll
            for (int d = 0; d < 3; d++) {
                float p = pseudo[e * 3 + d] * 4.0f;
                float l = fminf(fmaxf(floorf(p), 0.0f), 3.0f);
                c += (int)l * mul;
                mul <<= 2;
            }
            cube[e] = c;
            atomicAdd(&h[c], 1);
            atomicAdd(&dstCnt[edge[E + e]], 1);
        }
        __syncthreads();
        if (t < 64) blockCnt[rb * 64 + t] = h[t];
    } else if (b < HB1 + HB2 + HB3 + CVT2B) {
        int idx = (b - (HB1 + HB2 + HB3)) * 256 + t;
        if (idx < 125 * 64 * 64) {
            int ic = idx & 63, kn = idx >> 6;
            int n = kn & 63, k = kn >> 6;
            W2t[idx] = f2bf(W2[((size_t)k * 64 + ic) * 64 + n]);
        }
    } else if (b < HB1 + HB2 + HB3 + CVT2B + CVT3B) {
        int idx = (b - (HB1 + HB2 + HB3 + CVT2B)) * 256 + t;
        if (idx < 125 * 128 * 64) {
            int ic = idx & 63, kn = idx >> 6;
            int n = kn & 127, k = kn >> 7;
            W3t[idx] = f2bf(W3[((size_t)k * 64 + ic) * 128 + n]);
        }
    } else {
        int idx = (b - (HB1 + HB2 + HB3 + CVT2B + CVT3B)) * 256 + t;
        if (idx < N0c)
            atomicMax(&xm1[cluster0[idx]], f2sort(x0[idx]));
    }
}

// ---- STAGE B: all planning (scans, block offsets, chunk maps), one block ----
__global__ __launch_bounds__(256) void plan_all(
    const int* __restrict__ blockCnt1, int* __restrict__ start1,
    int* __restrict__ blockOff1,
    const int* __restrict__ blockCnt2, int* __restrict__ binCnt2,
    int* __restrict__ binStart2, int* __restrict__ blockOff2,
    int* __restrict__ blkPrefix2, int* __restrict__ chunkBin2,
    int* __restrict__ chunkOff2,
    const int* __restrict__ blockCnt3, int* __restrict__ binCnt3,
    int* __restrict__ binStart3, int* __restrict__ blockOff3,
    int* __restrict__ blkPrefix3, int* __restrict__ chunkBin3,
    int* __restrict__ chunkOff3)
{
    __shared__ int ps[256];
    __shared__ int tot64[64], ss64[64], ps64[64];
    int t = threadIdx.x;

    // conv1: thread t owns bins [5t, 5t+5)
    int loc[5];
    int s = 0;
    #pragma unroll
    for (int i = 0; i < 5; i++) {
        int bin = t * 5 + i;
        int v = 0;
        if (bin < 1250)
            for (int b = 0; b < HB1; b++) v += blockCnt1[b * 1250 + bin];
        loc[i] = v;
        s += v;
    }
    ps[t] = s;
    __syncthreads();
    for (int ofs = 1; ofs < 256; ofs <<= 1) {
        int add = (t >= ofs) ? ps[t - ofs] : 0;
        __syncthreads();
        ps[t] += add;
        __syncthreads();
    }
    int run = (t == 0) ? 0 : ps[t - 1];
    #pragma unroll
    for (int i = 0; i < 5; i++) {
        int bin = t * 5 + i;
        if (bin < 1250) {
            start1[bin] = run;
            int r2 = run;
            for (int b = 0; b < HB1; b++) {
                blockOff1[b * 1250 + bin] = r2;
                r2 += blockCnt1[b * 1250 + bin];
            }
            run += loc[i];
        }
    }
    if (t == 255) start1[1250] = run;

    // conv2 plan
    __syncthreads();
    if (t < 64) {
        int s2 = 0;
        for (int b = 0; b < HB2; b++) s2 += blockCnt2[b * 64 + t];
        tot64[t] = s2;
    }
    __syncthreads();
    if (t == 0) {
        int s2 = 0, p = 0;
        for (int c = 0; c < 64; c++) {
            ss64[c] = s2; ps64[c] = p;
            s2 += tot64[c];
            p += (tot64[c] + 31) >> 5;
        }
        blkPrefix2[64] = p;
    }
    __syncthreads();
    if (t < 64) {
        binCnt2[t] = tot64[t];
        binStart2[t] = ss64[t];
        blkPrefix2[t] = ps64[t];
        int r2 = ss64[t];
        for (int b = 0; b < HB2; b++) {
            blockOff2[b * 64 + t] = r2;
            r2 += blockCnt2[b * 64 + t];
        }
        int nch = (tot64[t] + 31) >> 5;
        for (int j = 0; j < nch; j++) {
            chunkBin2[ps64[t] + j] = t;
            chunkOff2[ps64[t] + j] = j;
        }
    }

    // conv3 plan
    __syncthreads();
    if (t < 64) {
        int s3 = 0;
        for (int b = 0; b < HB3; b++) s3 += blockCnt3[b * 64 + t];
        tot64[t] = s3;
    }
    __syncthreads();
    if (t == 0) {
        int s3 = 0, p = 0;
        for (int c = 0; c < 64; c++) {
            ss64[c] = s3; ps64[c] = p;
            s3 += tot64[c];
            p += (tot64[c] + 31) >> 5;
        }
        blkPrefix3[64] = p;
    }
    __syncthreads();
    if (t < 64) {
        binCnt3[t] = tot64[t];
        binStart3[t] = ss64[t];
        blkPrefix3[t] = ps64[t];
        int r3 = ss64[t];
        for (int b = 0; b < HB3; b++) {
            blockOff3[b * 64 + t] = r3;
            r3 += blockCnt3[b * 64 + t];
        }
        int nch = (tot64[t] + 31) >> 5;
        for (int j = 0; j < nch; j++) {
            chunkBin3[ps64[t] + j] = t;
            chunkOff3[ps64[t] + j] = j;
        }
    }
}

// ---- STAGE C: all scatters + pool0 decode, one kernel, blockIdx ranges ----
__global__ __launch_bounds__(256) void scatter_all(
    const int* __restrict__ edge1, const int* __restrict__ cube2,
    const int* __restrict__ cube3,
    const int* __restrict__ blockOff1, const int* __restrict__ blockOff2,
    const int* __restrict__ blockOff3,
    int* __restrict__ order1, int* __restrict__ order2, int* __restrict__ order3,
    unsigned* __restrict__ xm1)
{
    __shared__ int cur[1250];
    int b = blockIdx.x, t = threadIdx.x;
    if (b < HB1) {
        for (int i = t; i < 1250; i += 256) cur[i] = blockOff1[b * 1250 + i];
        __syncthreads();
        for (int e = b * 256 + t; e < E1c; e += HB1 * 256) {
            int p = atomicAdd(&cur[edge1[E1c + e] >> 4], 1);
            order1[p] = e;
        }
    } else if (b < HB1 + HB2 + HB3) {
        bool is2 = b < HB1 + HB2;
        int rb = is2 ? (b - HB1) : (b - HB1 - HB2);
        int nblk = is2 ? HB2 : HB3;
        int E = is2 ? E2c : E3c;
        const int* cube = is2 ? cube2 : cube3;
        const int* blockOff = is2 ? blockOff2 : blockOff3;
        int* order = is2 ? order2 : order3;
        if (t < 64) cur[t] = blockOff[rb * 64 + t];
        __syncthreads();
        for (int e = rb * 256 + t; e < E; e += nblk * 256) {
            int p = atomicAdd(&cur[cube[e]], 1);
            order[p] = e;
        }
    } else {
        int idx = (b - (HB1 + HB2 + HB3)) * 256 + t;
        if (idx < N1c) {
            float f = sort2f(xm1[idx]);
            unsigned bb = __float_as_uint(f);
            if ((bb & 0x7F800000u) == 0x7F800000u) f = 0.0f;
            ((float*)xm1)[idx] = f;
        }
    }
}

// ---- conv1 (C_in=1): per-16-node block, LDS knot accumulation + tiny GEMM,
// epilogue pools straight into xm2 (sortable-uint atomicMax). ----
__global__ __launch_bounds__(256) void conv1_block(
    const int* __restrict__ edge, const float* __restrict__ pseudo,
    const float* __restrict__ x,
    const int* __restrict__ start, const int* __restrict__ order,
    const float* __restrict__ W, const float* __restrict__ root,
    const float* __restrict__ bias, const int* __restrict__ cl,
    unsigned* __restrict__ xmOut) {
    __shared__ float T[16][128];
    __shared__ int degL[16];
    int b = blockIdx.x;
    for (int j = threadIdx.x; j < 2048; j += 256) ((float*)T)[j] = 0.0f;
    if (threadIdx.x < 16) degL[threadIdx.x] = 0;
    __syncthreads();
    int s0 = start[b], s1 = start[b + 1];
    for (int i = s0 + threadIdx.x; i < s1; i += 256) {
        int e = order[i];
        int src = edge[e], dst = edge[E1c + e];
        int ln = dst & 15;
        float xv = x[src];
        float f[3];
        int loi[3];
        #pragma unroll
        for (int d = 0; d < 3; d++) {
            float pp = pseudo[e * 3 + d] * 4.0f;
            float l = fminf(fmaxf(floorf(pp), 0.0f), 3.0f);
            f[d] = pp - l;
            loi[d] = (int)l;
        }
        int kbase = loi[0] + 5 * loi[1] + 25 * loi[2];
        #pragma unroll
        for (int s = 0; s < 8; s++) {
            int b0 = s & 1, b1 = (s >> 1) & 1, b2 = (s >> 2) & 1;
            float w0 = b0 ? f[0] : 1.0f - f[0];
            float w1 = b1 ? f[1] : 1.0f - f[1];
            float w2 = b2 ? f[2] : 1.0f - f[2];
            int k = kbase + b0 + 5 * b1 + 25 * b2;
            atomicAdd(&T[ln][k], xv * w0 * w1 * w2);
        }
        atomicAdd(&degL[ln], 1);
    }
    __syncthreads();
    int w = threadIdx.x >> 6, lane = threadIdx.x & 63;
    float acc[4] = {0.0f, 0.0f, 0.0f, 0.0f};
    for (int k = 0; k < 125; k++) {
        float wv = W[(k << 6) + lane];
        #pragma unroll
        for (int j = 0; j < 4; j++)
            acc[j] = fmaf(T[w + 4 * j][k], wv, acc[j]);
    }
    int v0 = b << 4;
    #pragma unroll
    for (int j = 0; j < 4; j++) {
        int ln = w + 4 * j;
        int v = v0 + ln;
        float d = fmaxf((float)degL[ln], 1.0f);
        float val = eluf(acc[j] / d + x[v] * root[lane] + bias[lane]);
        atomicMax(&xmOut[((size_t)cl[v] << 6) + lane], f2sort(val));
    }
}

// decode pooled sortable-uint buffer -> fp32 (in place) + bf16 copy
__global__ void decode_cvt(unsigned* __restrict__ buf,
                           unsigned short* __restrict__ xb, int total) {
    int idx = blockIdx.x * blockDim.x + threadIdx.x;
    if (idx >= total) return;
    float f = sort2f(buf[idx]);
    unsigned b = __float_as_uint(f);
    if ((b & 0x7F800000u) == 0x7F800000u) f = 0.0f;
    ((float*)buf)[idx] = f;
    xb[idx] = f2bf(f);
}

__global__ void segmax_decode(unsigned* __restrict__ buf, int total) {
    int idx = blockIdx.x * blockDim.x + threadIdx.x;
    if (idx >= total) return;
    float f = sort2f(buf[idx]);
    unsigned b = __float_as_uint(f);
    if ((b & 0x7F800000u) == 0x7F800000u) f = 0.0f;
    ((float*)buf)[idx] = f;
}

// Binned spline-conv via bf16 MFMA, independent waves, atomicAdd epilogue.
// Wave = 32 edges x 64 out-cols: 2 row-tiles x 4 N-tiles of 16x16x32.
// A-frags (pure x bf16) in regs reused over 8 taps; B batched per tap from L2;
// per-tap C scaled by basis (fp32) into acc; direct row-coalesced atomicAdd.
template<int COUT>
__global__ __launch_bounds__(256, 4) void spline_mfma(
    const int* __restrict__ edge, int E,
    const float* __restrict__ pseudo,
    const unsigned short* __restrict__ Wt,
    const unsigned short* __restrict__ xb,
    const int* __restrict__ order,
    const int* __restrict__ binStart,
    const int* __restrict__ binCnt,
    const int* __restrict__ blkPrefix,
    const int* __restrict__ chunkBin,
    const int* __restrict__ chunkOff,
    float* __restrict__ agg)
{
    __shared__ float basisS[4][8][32];
    __shared__ int srcS[4][32];
    __shared__ int dstS[4][32];

    int w = threadIdx.x >> 6, lane = threadIdx.x & 63;
    int c = blockIdx.x * 4 + w;
    if (c >= blkPrefix[64]) return;
    int bin = chunkBin[c];
    int chunk = chunkOff[c];
    int cnt = binCnt[bin];

    if (lane < 32) {
        int pos = chunk * 32 + lane;
        bool act = pos < cnt;
        int e = act ? order[binStart[bin] + pos] : 0;
        srcS[w][lane] = act ? edge[e] : 0;
        dstS[w][lane] = act ? edge[E + e] : -1;
        float f0 = 0.0f, f1 = 0.0f, f2 = 0.0f;
        if (act) {
            float p0 = pseudo[e * 3 + 0] * 4.0f;
            float p1 = pseudo[e * 3 + 1] * 4.0f;
            float p2 = pseudo[e * 3 + 2] * 4.0f;
            f0 = p0 - fminf(fmaxf(floorf(p0), 0.0f), 3.0f);
            f1 = p1 - fminf(fmaxf(floorf(p1), 0.0f), 3.0f);
            f2 = p2 - fminf(fmaxf(floorf(p2), 0.0f), 3.0f);
        }
        #pragma unroll
        for (int s = 0; s < 8; s++) {
            float w0 = (s & 1) ? f0 : 1.0f - f0;
            float w1 = (s & 2) ? f1 : 1.0f - f1;
            float w2 = (s & 4) ? f2 : 1.0f - f2;
            basisS[w][s][lane] = act ? (w0 * w1 * w2) : 0.0f;
        }
    }
    __builtin_amdgcn_wave_barrier();
    __threadfence_block();

    int lo0 = bin & 3, lo1 = (bin >> 2) & 3, lo2 = bin >> 4;
    int kbase = lo0 + 5 * lo1 + 25 * lo2;
    int colOff = (COUT == 128) ? (blockIdx.y << 6) : 0;
    int q = lane >> 4;        // quad
    int mcol = lane & 15;

    short8 afr[2][2];
    #pragma unroll
    for (int rt = 0; rt < 2; rt++) {
        int src = srcS[w][rt * 16 + mcol];
        const unsigned short* xr = xb + ((size_t)src << 6) + q * 8;
        afr[rt][0] = *(const short8*)(xr);
        afr[rt][1] = *(const short8*)(xr + 32);
    }

    f32x4 acc[2][4];
    #pragma unroll
    for (int rt = 0; rt < 2; rt++)
        #pragma unroll
        for (int nt = 0; nt < 4; nt++)
            acc[rt][nt] = (f32x4){0.0f, 0.0f, 0.0f, 0.0f};
    const f32x4 zero4 = {0.0f, 0.0f, 0.0f, 0.0f};

    #pragma unroll 2
    for (int s = 0; s < 8; s++) {
        int k = kbase + (s & 1) + 5 * ((s >> 1) & 1) + 25 * (s >> 2);
        const unsigned short* Wk = Wt + ((size_t)k * COUT + colOff) * 64;
        // batch all 8 B loads of this tap
        short8 bfr[4][2];
        #pragma unroll
        for (int nt = 0; nt < 4; nt++) {
            const unsigned short* Wn = Wk + (size_t)(nt * 16 + mcol) * 64 + q * 8;
            bfr[nt][0] = *(const short8*)(Wn);
            bfr[nt][1] = *(const short8*)(Wn + 32);
        }
        f32x4 ct[2][4];
        #pragma unroll
        for (int nt = 0; nt < 4; nt++) {
            ct[0][nt] = __builtin_amdgcn_mfma_f32_16x16x32_bf16(afr[0][0], bfr[nt][0], zero4, 0, 0, 0);
            ct[0][nt] = __builtin_amdgcn_mfma_f32_16x16x32_bf16(afr[0][1], bfr[nt][1], ct[0][nt], 0, 0, 0);
            ct[1][nt] = __builtin_amdgcn_mfma_f32_16x16x32_bf16(afr[1][0], bfr[nt][0], zero4, 0, 0, 0);
            ct[1][nt] = __builtin_amdgcn_mfma_f32_16x16x32_bf16(afr[1][1], bfr[nt][1], ct[1][nt], 0, 0, 0);
        }
        #pragma unroll
        for (int rt = 0; rt < 2; rt++)
            #pragma unroll
            for (int r = 0; r < 4; r++) {
                float bs = basisS[w][s][rt * 16 + q * 4 + r];
                #pragma unroll
                for (int nt = 0; nt < 4; nt++)
                    acc[rt][nt][r] = fmaf(bs, ct[rt][nt][r], acc[rt][nt][r]);
            }
    }

    // Epilogue: direct row-coalesced atomicAdd from C layout (row=q*4+r).
    #pragma unroll
    for (int rt = 0; rt < 2; rt++) {
        #pragma unroll
        for (int r = 0; r < 4; r++) {
            int d = dstS[w][rt * 16 + q * 4 + r];
            if (d >= 0) {
                float* ap = agg + (size_t)d * COUT + colOff + mcol;
                #pragma unroll
                for (int nt = 0; nt < 4; nt++)
                    atomicAdd(ap + nt * 16, acc[rt][nt][r]);
            }
        }
    }
}

// node update (mean + root matmul + bias + elu) + pool scatter, COUT=64.
__global__ __launch_bounds__(256) void node_update64(
    const float* __restrict__ agg, const int* __restrict__ deg,
    const float* __restrict__ xm, const float* __restrict__ root,
    const float* __restrict__ bias, const int* __restrict__ cl,
    unsigned* __restrict__ xmOut, int nNodes) {
    __shared__ float xsh[4][64];
    int w = threadIdx.x >> 6, lane = threadIdx.x & 63;
    int v = blockIdx.x * 4 + w;
    if (v >= nNodes) return;
    xsh[w][lane] = xm[((size_t)v << 6) + lane];
    float a = agg[((size_t)v << 6) + lane] / fmaxf((float)deg[v], 1.0f);
    float r = 0.0f;
    #pragma unroll 8
    for (int i = 0; i < 64; i++)
        r = fmaf(xsh[w][i], root[(i << 6) + lane], r);
    float val = eluf(a + r + bias[lane]);
    atomicMax(&xmOut[((size_t)cl[v] << 6) + lane], f2sort(val));
}

// node update + pool scatter, COUT=128 (2 channels/lane).
__global__ __launch_bounds__(256) void node_update128(
    const float* __restrict__ agg, const int* __restrict__ deg,
    const float* __restrict__ xm, const float* __restrict__ root,
    const float* __restrict__ bias, const int* __restrict__ cl,
    unsigned* __restrict__ xmOut, int nNodes) {
    __shared__ float xsh[4][64];
    int w = threadIdx.x >> 6, lane = threadIdx.x & 63;
    int v = blockIdx.x * 4 + w;
    if (v >= nNodes) return;
    xsh[w][lane] = xm[((size_t)v << 6) + lane];
    float dinv = 1.0f / fmaxf((float)deg[v], 1.0f);
    float a0 = agg[((size_t)v << 7) + lane] * dinv;
    float a1 = agg[((size_t)v << 7) + 64 + lane] * dinv;
    float r0 = 0.0f, r1 = 0.0f;
    #pragma unroll 8
    for (int i = 0; i < 64; i++) {
        float xi = xsh[w][i];
        r0 = fmaf(xi, root[(i << 7) + lane], r0);
        r1 = fmaf(xi, root[(i << 7) + 64 + lane], r1);
    }
    unsigned* orow = xmOut + ((size_t)cl[v] << 7);
    atomicMax(&orow[lane], f2sort(eluf(a0 + r0 + bias[lane])));
    atomicMax(&orow[64 + lane], f2sort(eluf(a1 + r1 + bias[lane + 64])));
}

// fused FC head: elu(x@fc1+b1) @ fc2 + b2, then log_softmax. One block/row.
__global__ __launch_bounds__(256) void fc_fused(
    const float* __restrict__ xin,
    const float* __restrict__ w1, const float* __restrict__ b1,
    const float* __restrict__ w2, const float* __restrict__ b2,
    float* __restrict__ out) {
    __shared__ float xsh[1024];
    __shared__ float hs[256];
    __shared__ float lg[10];
    int row = blockIdx.x;
    int o = threadIdx.x;
    for (int i = o; i < 1024; i += 256) xsh[i] = xin[row * 1024 + i];
    __syncthreads();
    float acc = b1[o];
    #pragma unroll 8
    for (int i = 0; i < 1024; i++) acc = fmaf(xsh[i], w1[i * 256 + o], acc);
    hs[o] = eluf(acc);
    __syncthreads();
    if (o < 10) {
        float a = b2[o];
        for (int i = 0; i < 256; i++) a = fmaf(hs[i], w2[i * 10 + o], a);
        lg[o] = a;
    }
    __syncthreads();
    if (o < 10) {
        float m = -1e30f;
        #pragma unroll
        for (int j = 0; j < 10; j++) m = fmaxf(m, lg[j]);
        float sum = 0.0f;
        #pragma unroll
        for (int j = 0; j < 10; j++) sum += expf(lg[j] - m);
        out[row * 10 + o] = lg[o] - m - logf(sum);
    }
}

extern "C" void kernel_launch(void* const* d_in, const int* in_sizes, int n_in,
                              void* d_out, int out_size, void* d_ws, size_t ws_size,
                              hipStream_t stream) {
    const float* x0      = (const float*)d_in[0];
    const int*   cluster0= (const int*)d_in[1];
    const int*   edge1   = (const int*)d_in[2];
    const float* pseudo1 = (const float*)d_in[3];
    const float* W1      = (const float*)d_in[4];
    const float* root1   = (const float*)d_in[5];
    const float* b1      = (const float*)d_in[6];
    const int*   cluster1= (const int*)d_in[7];
    const int*   edge2   = (const int*)d_in[8];
    const float* pseudo2 = (const float*)d_in[9];
    const float* W2      = (const float*)d_in[10];
    const float* root2   = (const float*)d_in[11];
    const float* b2      = (const float*)d_in[12];
    const int*   cluster2= (const int*)d_in[13];
    const int*   edge3   = (const int*)d_in[14];
    const float* pseudo3 = (const float*)d_in[15];
    const float* W3      = (const float*)d_in[16];
    const float* root3   = (const float*)d_in[17];
    const float* b3      = (const float*)d_in[18];
    const int*   cluster3= (const int*)d_in[19];
    const float* fc1_w   = (const float*)d_in[20];
    const float* fc1_b   = (const float*)d_in[21];
    const float* fc2_w   = (const float*)d_in[22];
    const float* fc2_b   = (const float*)d_in[23];
    float* out = (float*)d_out;

    float* ws = (float*)d_ws;
    size_t off = 0;
    // ---- zeroed region ----
    float* xm1  = ws + off; off += 20480;
    float* xm2  = ws + off; off += (size_t)N2c * 64;
    float* xm3  = ws + off; off += (size_t)N3c * 64;
    float* xm4  = ws + off; off += 512 * 128;
    float* agg2 = ws + off; off += (size_t)N2c * 64;
    float* agg3 = ws + off; off += (size_t)N3c * 128;
    int* cntD2   = (int*)(ws + off); off += 6016;
    int* cntD3   = (int*)(ws + off); off += 1664;
    size_t zeroFloats = off;
    // ---- non-zeroed region (fully written before read every launch) ----
    unsigned short* W2t = (unsigned short*)(ws + off); off += 256000;
    unsigned short* W3t = (unsigned short*)(ws + off); off += 512000;
    unsigned short* xb2 = (unsigned short*)(ws + off); off += 192000;
    unsigned short* xb3 = (unsigned short*)(ws + off); off += 51200;
    int* cube2     = (int*)(ws + off); off += E2c;
    int* order2    = (int*)(ws + off); off += E2c;
    int* cube3     = (int*)(ws + off); off += E3c;
    int* order3    = (int*)(ws + off); off += E3c;
    int* order1    = (int*)(ws + off); off += E1c;
    int* start1    = (int*)(ws + off); off += 1280;
    int* blockCnt1 = (int*)(ws + off); off += HB1 * 1250;
    int* blockOff1 = (int*)(ws + off); off += HB1 * 1250;
    int* blockCnt2 = (int*)(ws + off); off += HB2 * 64;
    int* blockOff2 = (int*)(ws + off); off += HB2 * 64;
    int* blockCnt3 = (int*)(ws + off); off += HB3 * 64;
    int* blockOff3 = (int*)(ws + off); off += HB3 * 64;
    int* binCnt2   = (int*)(ws + off); off += 64;
    int* binStart2 = (int*)(ws + off); off += 64;
    int* blkPrefix2= (int*)(ws + off); off += 80;
    int* chunkBin2 = (int*)(ws + off); off += 4608;
    int* chunkOff2 = (int*)(ws + off); off += 4608;
    int* binCnt3   = (int*)(ws + off); off += 64;
    int* binStart3 = (int*)(ws + off); off += 64;
    int* blkPrefix3= (int*)(ws + off); off += 80;
    int* chunkBin3 = (int*)(ws + off); off += 1280;
    int* chunkOff3 = (int*)(ws + off); off += 1280;

    hipMemsetAsync(d_ws, 0, zeroFloats * sizeof(float), stream);

    // A: all hists + cube compute + weight conversion + pool0 scatter
    hist_all<<<HB1 + HB2 + HB3 + CVT2B + CVT3B + SS0B, 256, 0, stream>>>(
        edge1, edge2, edge3, pseudo2, pseudo3, W2, W3, x0, cluster0,
        blockCnt1, cube2, blockCnt2, cntD2, cube3, blockCnt3, cntD3,
        W2t, W3t, (unsigned*)xm1);

    // B: all scans / offsets / chunk maps
    plan_all<<<1, 256, 0, stream>>>(
        blockCnt1, start1, blockOff1,
        blockCnt2, binCnt2, binStart2, blockOff2, blkPrefix2, chunkBin2, chunkOff2,
        blockCnt3, binCnt3, binStart3, blockOff3, blkPrefix3, chunkBin3, chunkOff3);

    // C: all scatters + pool0 decode
    scatter_all<<<HB1 + HB2 + HB3 + (N1c + 255) / 256, 256, 0, stream>>>(
        edge1, cube2, cube3, blockOff1, blockOff2, blockOff3,
        order1, order2, order3, (unsigned*)xm1);

    // conv1 (1->64) + pool into xm2
    conv1_block<<<1250, 256, 0, stream>>>(edge1, pseudo1, xm1, start1, order1,
                                          W1, root1, b1, cluster1, (unsigned*)xm2);
    decode_cvt<<<(N2c * 64) / 256, 256, 0, stream>>>((unsigned*)xm2, xb2, N2c * 64);

    // conv2 (64->64): MFMA -> agg2 (atomic), node update + pool into xm3
    spline_mfma<64><<<dim3((E2c / 32 + 64 + 3) / 4, 1), 256, 0, stream>>>(
        edge2, E2c, pseudo2, W2t, xb2, order2, binStart2, binCnt2, blkPrefix2,
        chunkBin2, chunkOff2, agg2);
    node_update64<<<(N2c + 3) / 4, 256, 0, stream>>>(agg2, cntD2, xm2, root2, b2,
                                                     cluster2, (unsigned*)xm3, N2c);
    decode_cvt<<<(N3c * 64) / 256, 256, 0, stream>>>((unsigned*)xm3, xb3, N3c * 64);

    // conv3 (64->128): MFMA -> agg3 (atomic), node update + pool into xm4
    spline_mfma<128><<<dim3((E3c / 32 + 64 + 3) / 4, 2), 256, 0, stream>>>(
        edge3, E3c, pseudo3, W3t, xb3, order3, binStart3, binCnt3, blkPrefix3,
        chunkBin3, chunkOff3, agg3);
    node_update128<<<(N3c + 3) / 4, 256, 0, stream>>>(agg3, cntD3, xm3, root3, b3,
                                                      cluster3, (unsigned*)xm4, N3c);
    segmax_decode<<<(512 * 128) / 256, 256, 0, stream>>>((unsigned*)xm4, 512 * 128);

    // FC head
    fc_fused<<<64, 256, 0, stream>>>(xm4, fc1_w, fc1_b, fc2_w, fc2_b, out);
}

// Round 10
// 381.190 us; speedup vs baseline: 3.6678x; 1.0719x over previous
//
#include <hip/hip_runtime.h>
#include <hip/hip_bf16.h>
#include <math.h>

#define N0c 120000
#define N1c 20000
#define N2c 6000
#define N3c 1600
#define E1c 480000
#define E2c 144000
#define E3c 38400

#define HB1 120   // hist/scatter blocks for conv1 (1250 bins of dst>>4)
#define HB2 120   // hist/scatter blocks for conv2 cube sort
#define HB3 40    // hist/scatter blocks for conv3 cube sort
#define CVT2B 2000  // 125*64*64/256
#define CVT3B 4000  // 125*128*64/256
#define SS0B  469   // (120000+255)/256

typedef __attribute__((ext_vector_type(8))) short short8;
typedef __attribute__((ext_vector_type(4))) float f32x4;

__device__ __forceinline__ float eluf(float x) {
    return x > 0.0f ? x : expm1f(x);
}

__device__ __forceinline__ unsigned f2sort(float f) {
    unsigned u = __float_as_uint(f);
    return (u & 0x80000000u) ? ~u : (u | 0x80000000u);
}
__device__ __forceinline__ float sort2f(unsigned u) {
    unsigned bits = (u & 0x80000000u) ? (u & 0x7FFFFFFFu) : ~u;
    return __uint_as_float(bits);
}
__device__ __forceinline__ unsigned short f2bf(float v) {
    unsigned u = __float_as_uint(v);
    unsigned r = (u + 0x7FFFu + ((u >> 16) & 1u)) >> 16;   // RNE
    return (unsigned short)r;
}

// ---- STAGE A: all feature-independent prep, one kernel, blockIdx ranges ----
__global__ __launch_bounds__(256) void hist_all(
    const int* __restrict__ edge1, const int* __restrict__ edge2,
    const int* __restrict__ edge3,
    const float* __restrict__ pseudo2, const float* __restrict__ pseudo3,
    const float* __restrict__ W2, const float* __restrict__ W3,
    const float* __restrict__ x0, const int* __restrict__ cluster0,
    int* __restrict__ blockCnt1,
    int* __restrict__ blockCnt2, int* __restrict__ cntD2,
    int* __restrict__ blockCnt3, int* __restrict__ cntD3,
    unsigned short* __restrict__ W2t, unsigned short* __restrict__ W3t,
    unsigned* __restrict__ xm1)
{
    __shared__ int h[1250];
    int b = blockIdx.x, t = threadIdx.x;
    if (b < HB1) {
        for (int i = t; i < 1250; i += 256) h[i] = 0;
        __syncthreads();
        for (int e = b * 256 + t; e < E1c; e += HB1 * 256)
            atomicAdd(&h[edge1[E1c + e] >> 4], 1);
        __syncthreads();
        for (int i = t; i < 1250; i += 256) blockCnt1[i * HB1 + b] = h[i];
    } else if (b < HB1 + HB2 + HB3) {
        bool is2 = b < HB1 + HB2;
        int rb = is2 ? (b - HB1) : (b - HB1 - HB2);
        int nblk = is2 ? HB2 : HB3;
        int E = is2 ? E2c : E3c;
        const int* edge = is2 ? edge2 : edge3;
        const float* pseudo = is2 ? pseudo2 : pseudo3;
        int* blockCnt = is2 ? blockCnt2 : blockCnt3;
        int* dstCnt = is2 ? cntD2 : cntD3;
        int nb = is2 ? HB2 : HB3;
        if (t < 64) h[t] = 0;
        __syncthreads();
        for (int e = rb * 256 + t; e < E; e += nblk * 256) {
            int c = 0, mul = 1;
            #pragma unroll
            for (int d = 0; d < 3; d++) {
                float p = pseudo[e * 3 + d] * 4.0f;
                float l = fminf(fmaxf(floorf(p), 0.0f), 3.0f);
                c += (int)l * mul;
                mul <<= 2;
            }
            atomicAdd(&h[c], 1);
            atomicAdd(&dstCnt[edge[E + e]], 1);
        }
        __syncthreads();
        if (t < 64) blockCnt[t * nb + rb] = h[t];
    } else if (b < HB1 + HB2 + HB3 + CVT2B) {
        int idx = (b - (HB1 + HB2 + HB3)) * 256 + t;
        if (idx < 125 * 64 * 64) {
            int ic = idx & 63, kn = idx >> 6;
            int n = kn & 63, k = kn >> 6;
            W2t[idx] = f2bf(W2[((size_t)k * 64 + ic) * 64 + n]);
        }
    } else if (b < HB1 + HB2 + HB3 + CVT2B + CVT3B) {
        int idx = (b - (HB1 + HB2 + HB3 + CVT2B)) * 256 + t;
        if (idx < 125 * 128 * 64) {
            int ic = idx & 63, kn = idx >> 6;
            int n = kn & 127, k = kn >> 7;
            W3t[idx] = f2bf(W3[((size_t)k * 64 + ic) * 128 + n]);
        }
    } else {
        int idx = (b - (HB1 + HB2 + HB3 + CVT2B + CVT3B)) * 256 + t;
        if (idx < N0c)
            atomicMax(&xm1[cluster0[idx]], f2sort(x0[idx]));
    }
}

// ---- STAGE B: all planning; transposed blockCnt layouts for coalesced sums ----
__global__ __launch_bounds__(256) void plan_all(
    const int* __restrict__ blockCnt1, int* __restrict__ start1,
    int* __restrict__ blockOff1,
    const int* __restrict__ blockCnt2, int* __restrict__ binCnt2,
    int* __restrict__ binStart2, int* __restrict__ blockOff2,
    int* __restrict__ blkPrefix2, int* __restrict__ chunkBin2,
    int* __restrict__ chunkOff2,
    const int* __restrict__ blockCnt3, int* __restrict__ binCnt3,
    int* __restrict__ binStart3, int* __restrict__ blockOff3,
    int* __restrict__ blkPrefix3, int* __restrict__ chunkBin3,
    int* __restrict__ chunkOff3)
{
    __shared__ int ps[256];
    __shared__ int tot64[64], ss64[64], ps64[64];
    int t = threadIdx.x;

    // conv1: thread t owns bins [5t, 5t+5); blockCnt1 is [bin][blk]
    int loc[5];
    int s = 0;
    #pragma unroll
    for (int i = 0; i < 5; i++) {
        int bin = t * 5 + i;
        int v = 0;
        if (bin < 1250) {
            const int* row = blockCnt1 + (size_t)bin * HB1;
            for (int b = 0; b < HB1; b++) v += row[b];
        }
        loc[i] = v;
        s += v;
    }
    ps[t] = s;
    __syncthreads();
    for (int ofs = 1; ofs < 256; ofs <<= 1) {
        int add = (t >= ofs) ? ps[t - ofs] : 0;
        __syncthreads();
        ps[t] += add;
        __syncthreads();
    }
    int run = (t == 0) ? 0 : ps[t - 1];
    #pragma unroll
    for (int i = 0; i < 5; i++) {
        int bin = t * 5 + i;
        if (bin < 1250) {
            start1[bin] = run;
            const int* crow = blockCnt1 + (size_t)bin * HB1;
            int* orow = blockOff1 + (size_t)bin * HB1;
            int r2 = run;
            for (int b = 0; b < HB1; b++) {
                orow[b] = r2;
                r2 += crow[b];
            }
            run += loc[i];
        }
    }
    if (t == 255) start1[1250] = run;

    // conv2 plan (chunk = 64 edges)
    __syncthreads();
    if (t < 64) {
        int s2 = 0;
        const int* row = blockCnt2 + (size_t)t * HB2;
        for (int b = 0; b < HB2; b++) s2 += row[b];
        tot64[t] = s2;
    }
    __syncthreads();
    if (t == 0) {
        int s2 = 0, p = 0;
        for (int c = 0; c < 64; c++) {
            ss64[c] = s2; ps64[c] = p;
            s2 += tot64[c];
            p += (tot64[c] + 63) >> 6;
        }
        blkPrefix2[64] = p;
    }
    __syncthreads();
    if (t < 64) {
        binCnt2[t] = tot64[t];
        binStart2[t] = ss64[t];
        blkPrefix2[t] = ps64[t];
        const int* crow = blockCnt2 + (size_t)t * HB2;
        int* orow = blockOff2 + (size_t)t * HB2;
        int r2 = ss64[t];
        for (int b = 0; b < HB2; b++) {
            orow[b] = r2;
            r2 += crow[b];
        }
        int nch = (tot64[t] + 63) >> 6;
        for (int j = 0; j < nch; j++) {
            chunkBin2[ps64[t] + j] = t;
            chunkOff2[ps64[t] + j] = j;
        }
    }

    // conv3 plan
    __syncthreads();
    if (t < 64) {
        int s3 = 0;
        const int* row = blockCnt3 + (size_t)t * HB3;
        for (int b = 0; b < HB3; b++) s3 += row[b];
        tot64[t] = s3;
    }
    __syncthreads();
    if (t == 0) {
        int s3 = 0, p = 0;
        for (int c = 0; c < 64; c++) {
            ss64[c] = s3; ps64[c] = p;
            s3 += tot64[c];
            p += (tot64[c] + 63) >> 6;
        }
        blkPrefix3[64] = p;
    }
    __syncthreads();
    if (t < 64) {
        binCnt3[t] = tot64[t];
        binStart3[t] = ss64[t];
        blkPrefix3[t] = ps64[t];
        const int* crow = blockCnt3 + (size_t)t * HB3;
        int* orow = blockOff3 + (size_t)t * HB3;
        int r3 = ss64[t];
        for (int b = 0; b < HB3; b++) {
            orow[b] = r3;
            r3 += crow[b];
        }
        int nch = (tot64[t] + 63) >> 6;
        for (int j = 0; j < nch; j++) {
            chunkBin3[ps64[t] + j] = t;
            chunkOff3[ps64[t] + j] = j;
        }
    }
}

// ---- STAGE C: scatter EDGE RECORDS (coalesced reads, scattered writes) ----
// rec = int4 { meta, f0, f1, f2 }.
// conv1 meta: src | (dst&15)<<16 | kbase<<20.  conv2/3 meta: src | dst<<16.
__global__ __launch_bounds__(256) void scatter_all(
    const int* __restrict__ edge1, const float* __restrict__ pseudo1,
    const int* __restrict__ edge2, const float* __restrict__ pseudo2,
    const int* __restrict__ edge3, const float* __restrict__ pseudo3,
    const int* __restrict__ blockOff1, const int* __restrict__ blockOff2,
    const int* __restrict__ blockOff3,
    int4* __restrict__ rec1, int4* __restrict__ rec2, int4* __restrict__ rec3,
    unsigned* __restrict__ xm1)
{
    __shared__ int cur[1250];
    int b = blockIdx.x, t = threadIdx.x;
    if (b < HB1) {
        for (int i = t; i < 1250; i += 256) cur[i] = blockOff1[(size_t)i * HB1 + b];
        __syncthreads();
        for (int e = b * 256 + t; e < E1c; e += HB1 * 256) {
            int src = edge1[e], dst = edge1[E1c + e];
            float f[3];
            int kbase = 0, mul5 = 1;
            #pragma unroll
            for (int d = 0; d < 3; d++) {
                float pp = pseudo1[e * 3 + d] * 4.0f;
                float l = fminf(fmaxf(floorf(pp), 0.0f), 3.0f);
                f[d] = pp - l;
                kbase += (int)l * mul5;
                mul5 *= 5;
            }
            int p = atomicAdd(&cur[dst >> 4], 1);
            rec1[p] = make_int4(src | ((dst & 15) << 16) | (kbase << 20),
                                __float_as_int(f[0]), __float_as_int(f[1]),
                                __float_as_int(f[2]));
        }
    } else if (b < HB1 + HB2 + HB3) {
        bool is2 = b < HB1 + HB2;
        int rb = is2 ? (b - HB1) : (b - HB1 - HB2);
        int nblk = is2 ? HB2 : HB3;
        int E = is2 ? E2c : E3c;
        const int* edge = is2 ? edge2 : edge3;
        const float* pseudo = is2 ? pseudo2 : pseudo3;
        const int* blockOff = is2 ? blockOff2 : blockOff3;
        int4* rec = is2 ? rec2 : rec3;
        int nb = is2 ? HB2 : HB3;
        if (t < 64) cur[t] = blockOff[(size_t)t * nb + rb];
        __syncthreads();
        for (int e = rb * 256 + t; e < E; e += nblk * 256) {
            int src = edge[e], dst = edge[E + e];
            float f[3];
            int c = 0, mul = 1;
            #pragma unroll
            for (int d = 0; d < 3; d++) {
                float pp = pseudo[e * 3 + d] * 4.0f;
                float l = fminf(fmaxf(floorf(pp), 0.0f), 3.0f);
                f[d] = pp - l;
                c += (int)l * mul;
                mul <<= 2;
            }
            int p = atomicAdd(&cur[c], 1);
            rec[p] = make_int4(src | (dst << 16),
                               __float_as_int(f[0]), __float_as_int(f[1]),
                               __float_as_int(f[2]));
        }
    } else {
        int idx = (b - (HB1 + HB2 + HB3)) * 256 + t;
        if (idx < N1c) {
            float f = sort2f(xm1[idx]);
            unsigned bb = __float_as_uint(f);
            if ((bb & 0x7F800000u) == 0x7F800000u) f = 0.0f;
            ((float*)xm1)[idx] = f;
        }
    }
}

// ---- conv1 (C_in=1): per-16-node block, LDS knot accumulation + tiny GEMM,
// epilogue pools straight into xm2 (sortable-uint atomicMax). Reads records.
__global__ __launch_bounds__(256) void conv1_block(
    const int4* __restrict__ rec, const float* __restrict__ x,
    const int* __restrict__ start,
    const float* __restrict__ W, const float* __restrict__ root,
    const float* __restrict__ bias, const int* __restrict__ cl,
    unsigned* __restrict__ xmOut) {
    __shared__ float T[16][128];
    __shared__ int degL[16];
    int b = blockIdx.x;
    for (int j = threadIdx.x; j < 2048; j += 256) ((float*)T)[j] = 0.0f;
    if (threadIdx.x < 16) degL[threadIdx.x] = 0;
    __syncthreads();
    int s0 = start[b], s1 = start[b + 1];
    for (int i = s0 + threadIdx.x; i < s1; i += 256) {
        int4 r = rec[i];
        int src = r.x & 0xFFFF;
        int ln = (r.x >> 16) & 15;
        int kbase = r.x >> 20;
        float f0 = __int_as_float(r.y);
        float f1 = __int_as_float(r.z);
        float f2 = __int_as_float(r.w);
        float xv = x[src];
        #pragma unroll
        for (int s = 0; s < 8; s++) {
            int b0 = s & 1, b1 = (s >> 1) & 1, b2 = (s >> 2) & 1;
            float w0 = b0 ? f0 : 1.0f - f0;
            float w1 = b1 ? f1 : 1.0f - f1;
            float w2 = b2 ? f2 : 1.0f - f2;
            int k = kbase + b0 + 5 * b1 + 25 * b2;
            atomicAdd(&T[ln][k], xv * w0 * w1 * w2);
        }
        atomicAdd(&degL[ln], 1);
    }
    __syncthreads();
    int w = threadIdx.x >> 6, lane = threadIdx.x & 63;
    float acc[4] = {0.0f, 0.0f, 0.0f, 0.0f};
    for (int k = 0; k < 125; k++) {
        float wv = W[(k << 6) + lane];
        #pragma unroll
        for (int j = 0; j < 4; j++)
            acc[j] = fmaf(T[w + 4 * j][k], wv, acc[j]);
    }
    int v0 = b << 4;
    #pragma unroll
    for (int j = 0; j < 4; j++) {
        int ln = w + 4 * j;
        int v = v0 + ln;
        float d = fmaxf((float)degL[ln], 1.0f);
        float val = eluf(acc[j] / d + x[v] * root[lane] + bias[lane]);
        atomicMax(&xmOut[((size_t)cl[v] << 6) + lane], f2sort(val));
    }
}

// decode pooled sortable-uint buffer -> fp32 (in place) + bf16 copy
__global__ void decode_cvt(unsigned* __restrict__ buf,
                           unsigned short* __restrict__ xb, int total) {
    int idx = blockIdx.x * blockDim.x + threadIdx.x;
    if (idx >= total) return;
    float f = sort2f(buf[idx]);
    unsigned b = __float_as_uint(f);
    if ((b & 0x7F800000u) == 0x7F800000u) f = 0.0f;
    ((float*)buf)[idx] = f;
    xb[idx] = f2bf(f);
}

__global__ void segmax_decode(unsigned* __restrict__ buf, int total) {
    int idx = blockIdx.x * blockDim.x + threadIdx.x;
    if (idx >= total) return;
    float f = sort2f(buf[idx]);
    unsigned b = __float_as_uint(f);
    if ((b & 0x7F800000u) == 0x7F800000u) f = 0.0f;
    ((float*)buf)[idx] = f;
}

// Binned spline-conv via bf16 MFMA. Wave = 64 edges x 64 cols:
// 4 row-tiles x 4 N-tiles of 16x16x32. A-frags in regs reused over 8 taps;
// B batched per tap from L2; per-tap C scaled by basis; coalesced atomicAdd.
template<int COUT>
__global__ __launch_bounds__(256) void spline_mfma(
    const int4* __restrict__ recs,
    const unsigned short* __restrict__ Wt,
    const unsigned short* __restrict__ xb,
    const int* __restrict__ binStart,
    const int* __restrict__ binCnt,
    const int* __restrict__ blkPrefix,
    const int* __restrict__ chunkBin,
    const int* __restrict__ chunkOff,
    float* __restrict__ agg)
{
    __shared__ float basisS[4][8][64];
    __shared__ int srcS[4][64];
    __shared__ int dstS[4][64];

    int w = threadIdx.x >> 6, lane = threadIdx.x & 63;
    int c = blockIdx.x * 4 + w;
    if (c >= blkPrefix[64]) return;
    int bin = chunkBin[c];
    int chunk = chunkOff[c];
    int cnt = binCnt[bin];

    {
        int pos = chunk * 64 + lane;
        bool act = pos < cnt;
        int4 r = act ? recs[binStart[bin] + pos] : make_int4(0, 0, 0, 0);
        srcS[w][lane] = r.x & 0xFFFF;
        dstS[w][lane] = act ? (r.x >> 16) : -1;
        float f0 = __int_as_float(r.y);
        float f1 = __int_as_float(r.z);
        float f2 = __int_as_float(r.w);
        #pragma unroll
        for (int s = 0; s < 8; s++) {
            float w0 = (s & 1) ? f0 : 1.0f - f0;
            float w1 = (s & 2) ? f1 : 1.0f - f1;
            float w2 = (s & 4) ? f2 : 1.0f - f2;
            basisS[w][s][lane] = act ? (w0 * w1 * w2) : 0.0f;
        }
    }
    __builtin_amdgcn_wave_barrier();
    __threadfence_block();

    int lo0 = bin & 3, lo1 = (bin >> 2) & 3, lo2 = bin >> 4;
    int kbase = lo0 + 5 * lo1 + 25 * lo2;
    int colOff = (COUT == 128) ? (blockIdx.y << 6) : 0;
    int q = lane >> 4;        // quad
    int mcol = lane & 15;

    short8 afr[4][2];
    #pragma unroll
    for (int rt = 0; rt < 4; rt++) {
        int src = srcS[w][rt * 16 + mcol];
        const unsigned short* xr = xb + ((size_t)src << 6) + q * 8;
        afr[rt][0] = *(const short8*)(xr);
        afr[rt][1] = *(const short8*)(xr + 32);
    }

    f32x4 acc[4][4];
    #pragma unroll
    for (int rt = 0; rt < 4; rt++)
        #pragma unroll
        for (int nt = 0; nt < 4; nt++)
            acc[rt][nt] = (f32x4){0.0f, 0.0f, 0.0f, 0.0f};
    const f32x4 zero4 = {0.0f, 0.0f, 0.0f, 0.0f};

    #pragma unroll 1
    for (int s = 0; s < 8; s++) {
        int k = kbase + (s & 1) + 5 * ((s >> 1) & 1) + 25 * (s >> 2);
        const unsigned short* Wk = Wt + ((size_t)k * COUT + colOff) * 64;
        short8 bfr[4][2];
        #pragma unroll
        for (int nt = 0; nt < 4; nt++) {
            const unsigned short* Wn = Wk + (size_t)(nt * 16 + mcol) * 64 + q * 8;
            bfr[nt][0] = *(const short8*)(Wn);
            bfr[nt][1] = *(const short8*)(Wn + 32);
        }
        #pragma unroll
        for (int rt = 0; rt < 4; rt++) {
            f32x4 ct[4];
            #pragma unroll
            for (int nt = 0; nt < 4; nt++) {
                ct[nt] = __builtin_amdgcn_mfma_f32_16x16x32_bf16(afr[rt][0], bfr[nt][0], zero4, 0, 0, 0);
                ct[nt] = __builtin_amdgcn_mfma_f32_16x16x32_bf16(afr[rt][1], bfr[nt][1], ct[nt], 0, 0, 0);
            }
            #pragma unroll
            for (int r = 0; r < 4; r++) {
                float bs = basisS[w][s][rt * 16 + q * 4 + r];
                #pragma unroll
                for (int nt = 0; nt < 4; nt++)
                    acc[rt][nt][r] = fmaf(bs, ct[nt][r], acc[rt][nt][r]);
            }
        }
    }

    // Epilogue: row-coalesced atomicAdd from C layout (row = q*4+r).
    #pragma unroll
    for (int rt = 0; rt < 4; rt++) {
        #pragma unroll
        for (int r = 0; r < 4; r++) {
            int d = dstS[w][rt * 16 + q * 4 + r];
            if (d >= 0) {
                float* ap = agg + (size_t)d * COUT + colOff + mcol;
                #pragma unroll
                for (int nt = 0; nt < 4; nt++)
                    atomicAdd(ap + nt * 16, acc[rt][nt][r]);
            }
        }
    }
}

// node update (mean + root matmul + bias + elu) + pool scatter, COUT=64.
__global__ __launch_bounds__(256) void node_update64(
    const float* __restrict__ agg, const int* __restrict__ deg,
    const float* __restrict__ xm, const float* __restrict__ root,
    const float* __restrict__ bias, const int* __restrict__ cl,
    unsigned* __restrict__ xmOut, int nNodes) {
    __shared__ float xsh[4][64];
    int w = threadIdx.x >> 6, lane = threadIdx.x & 63;
    int v = blockIdx.x * 4 + w;
    if (v >= nNodes) return;
    xsh[w][lane] = xm[((size_t)v << 6) + lane];
    float a = agg[((size_t)v << 6) + lane] / fmaxf((float)deg[v], 1.0f);
    float r = 0.0f;
    #pragma unroll 8
    for (int i = 0; i < 64; i++)
        r = fmaf(xsh[w][i], root[(i << 6) + lane], r);
    float val = eluf(a + r + bias[lane]);
    atomicMax(&xmOut[((size_t)cl[v] << 6) + lane], f2sort(val));
}

// node update + pool scatter, COUT=128 (2 channels/lane).
__global__ __launch_bounds__(256) void node_update128(
    const float* __restrict__ agg, const int* __restrict__ deg,
    const float* __restrict__ xm, const float* __restrict__ root,
    const float* __restrict__ bias, const int* __restrict__ cl,
    unsigned* __restrict__ xmOut, int nNodes) {
    __shared__ float xsh[4][64];
    int w = threadIdx.x >> 6, lane = threadIdx.x & 63;
    int v = blockIdx.x * 4 + w;
    if (v >= nNodes) return;
    xsh[w][lane] = xm[((size_t)v << 6) + lane];
    float dinv = 1.0f / fmaxf((float)deg[v], 1.0f);
    float a0 = agg[((size_t)v << 7) + lane] * dinv;
    float a1 = agg[((size_t)v << 7) + 64 + lane] * dinv;
    float r0 = 0.0f, r1 = 0.0f;
    #pragma unroll 8
    for (int i = 0; i < 64; i++) {
        float xi = xsh[w][i];
        r0 = fmaf(xi, root[(i << 7) + lane], r0);
        r1 = fmaf(xi, root[(i << 7) + 64 + lane], r1);
    }
    unsigned* orow = xmOut + ((size_t)cl[v] << 7);
    atomicMax(&orow[lane], f2sort(eluf(a0 + r0 + bias[lane])));
    atomicMax(&orow[64 + lane], f2sort(eluf(a1 + r1 + bias[lane + 64])));
}

// fused FC head: elu(x@fc1+b1) @ fc2 + b2, then log_softmax. One block/row.
__global__ __launch_bounds__(256) void fc_fused(
    const float* __restrict__ xin,
    const float* __restrict__ w1, const float* __restrict__ b1,
    const float* __restrict__ w2, const float* __restrict__ b2,
    float* __restrict__ out) {
    __shared__ float xsh[1024];
    __shared__ float hs[256];
    __shared__ float lg[10];
    int row = blockIdx.x;
    int o = threadIdx.x;
    for (int i = o; i < 1024; i += 256) xsh[i] = xin[row * 1024 + i];
    __syncthreads();
    float acc = b1[o];
    #pragma unroll 8
    for (int i = 0; i < 1024; i++) acc = fmaf(xsh[i], w1[i * 256 + o], acc);
    hs[o] = eluf(acc);
    __syncthreads();
    if (o < 10) {
        float a = b2[o];
        for (int i = 0; i < 256; i++) a = fmaf(hs[i], w2[i * 10 + o], a);
        lg[o] = a;
    }
    __syncthreads();
    if (o < 10) {
        float m = -1e30f;
        #pragma unroll
        for (int j = 0; j < 10; j++) m = fmaxf(m, lg[j]);
        float sum = 0.0f;
        #pragma unroll
        for (int j = 0; j < 10; j++) sum += expf(lg[j] - m);
        out[row * 10 + o] = lg[o] - m - logf(sum);
    }
}

extern "C" void kernel_launch(void* const* d_in, const int* in_sizes, int n_in,
                              void* d_out, int out_size, void* d_ws, size_t ws_size,
                              hipStream_t stream) {
    const float* x0      = (const float*)d_in[0];
    const int*   cluster0= (const int*)d_in[1];
    const int*   edge1   = (const int*)d_in[2];
    const float* pseudo1 = (const float*)d_in[3];
    const float* W1      = (const float*)d_in[4];
    const float* root1   = (const float*)d_in[5];
    const float* b1      = (const float*)d_in[6];
    const int*   cluster1= (const int*)d_in[7];
    const int*   edge2   = (const int*)d_in[8];
    const float* pseudo2 = (const float*)d_in[9];
    const float* W2      = (const float*)d_in[10];
    const float* root2   = (const float*)d_in[11];
    const float* b2      = (const float*)d_in[12];
    const int*   cluster2= (const int*)d_in[13];
    const int*   edge3   = (const int*)d_in[14];
    const float* pseudo3 = (const float*)d_in[15];
    const float* W3      = (const float*)d_in[16];
    const float* root3   = (const float*)d_in[17];
    const float* b3      = (const float*)d_in[18];
    const int*   cluster3= (const int*)d_in[19];
    const float* fc1_w   = (const float*)d_in[20];
    const float* fc1_b   = (const float*)d_in[21];
    const float* fc2_w   = (const float*)d_in[22];
    const float* fc2_b   = (const float*)d_in[23];
    float* out = (float*)d_out;

    float* ws = (float*)d_ws;
    size_t off = 0;
    // ---- zeroed region ----
    float* xm1  = ws + off; off += 20480;
    float* xm2  = ws + off; off += (size_t)N2c * 64;
    float* xm3  = ws + off; off += (size_t)N3c * 64;
    float* xm4  = ws + off; off += 512 * 128;
    float* agg2 = ws + off; off += (size_t)N2c * 64;
    float* agg3 = ws + off; off += (size_t)N3c * 128;
    int* cntD2   = (int*)(ws + off); off += 6016;
    int* cntD3   = (int*)(ws + off); off += 1664;
    size_t zeroFloats = off;
    // ---- non-zeroed region (fully written before read every launch) ----
    int4* rec1 = (int4*)(ws + off); off += (size_t)E1c * 4;
    int4* rec2 = (int4*)(ws + off); off += (size_t)E2c * 4;
    int4* rec3 = (int4*)(ws + off); off += (size_t)E3c * 4;
    unsigned short* W2t = (unsigned short*)(ws + off); off += 256000;
    unsigned short* W3t = (unsigned short*)(ws + off); off += 512000;
    unsigned short* xb2 = (unsigned short*)(ws + off); off += 192000;
    unsigned short* xb3 = (unsigned short*)(ws + off); off += 51200;
    int* start1    = (int*)(ws + off); off += 1280;
    int* blockCnt1 = (int*)(ws + off); off += HB1 * 1250;
    int* blockOff1 = (int*)(ws + off); off += HB1 * 1250;
    int* blockCnt2 = (int*)(ws + off); off += HB2 * 64;
    int* blockOff2 = (int*)(ws + off); off += HB2 * 64;
    int* blockCnt3 = (int*)(ws + off); off += HB3 * 64;
    int* blockOff3 = (int*)(ws + off); off += HB3 * 64;
    int* binCnt2   = (int*)(ws + off); off += 64;
    int* binStart2 = (int*)(ws + off); off += 64;
    int* blkPrefix2= (int*)(ws + off); off += 80;
    int* chunkBin2 = (int*)(ws + off); off += 2560;
    int* chunkOff2 = (int*)(ws + off); off += 2560;
    int* binCnt3   = (int*)(ws + off); off += 64;
    int* binStart3 = (int*)(ws + off); off += 64;
    int* blkPrefix3= (int*)(ws + off); off += 80;
    int* chunkBin3 = (int*)(ws + off); off += 768;
    int* chunkOff3 = (int*)(ws + off); off += 768;

    hipMemsetAsync(d_ws, 0, zeroFloats * sizeof(float), stream);

    // A: hists + dst-degrees + weight conversion + pool0 scatter
    hist_all<<<HB1 + HB2 + HB3 + CVT2B + CVT3B + SS0B, 256, 0, stream>>>(
        edge1, edge2, edge3, pseudo2, pseudo3, W2, W3, x0, cluster0,
        blockCnt1, blockCnt2, cntD2, blockCnt3, cntD3,
        W2t, W3t, (unsigned*)xm1);

    // B: scans / offsets / chunk maps
    plan_all<<<1, 256, 0, stream>>>(
        blockCnt1, start1, blockOff1,
        blockCnt2, binCnt2, binStart2, blockOff2, blkPrefix2, chunkBin2, chunkOff2,
        blockCnt3, binCnt3, binStart3, blockOff3, blkPrefix3, chunkBin3, chunkOff3);

    // C: scatter edge records + pool0 decode
    scatter_all<<<HB1 + HB2 + HB3 + (N1c + 255) / 256, 256, 0, stream>>>(
        edge1, pseudo1, edge2, pseudo2, edge3, pseudo3,
        blockOff1, blockOff2, blockOff3, rec1, rec2, rec3, (unsigned*)xm1);

    // conv1 (1->64) + pool into xm2
    conv1_block<<<1250, 256, 0, stream>>>(rec1, xm1, start1, W1, root1, b1,
                                          cluster1, (unsigned*)xm2);
    decode_cvt<<<(N2c * 64) / 256, 256, 0, stream>>>((unsigned*)xm2, xb2, N2c * 64);

    // conv2 (64->64): MFMA -> agg2 (atomic), node update + pool into xm3
    spline_mfma<64><<<dim3((E2c / 64 + 64 + 3) / 4, 1), 256, 0, stream>>>(
        rec2, W2t, xb2, binStart2, binCnt2, blkPrefix2, chunkBin2, chunkOff2, agg2);
    node_update64<<<(N2c + 3) / 4, 256, 0, stream>>>(agg2, cntD2, xm2, root2, b2,
                                                     cluster2, (unsigned*)xm3, N2c);
    decode_cvt<<<(N3c * 64) / 256, 256, 0, stream>>>((unsigned*)xm3, xb3, N3c * 64);

    // conv3 (64->128): MFMA -> agg3 (atomic), node update + pool into xm4
    spline_mfma<128><<<dim3((E3c / 64 + 64 + 3) / 4, 2), 256, 0, stream>>>(
        rec3, W3t, xb3, binStart3, binCnt3, blkPrefix3, chunkBin3, chunkOff3, agg3);
    node_update128<<<(N3c + 3) / 4, 256, 0, stream>>>(agg3, cntD3, xm3, root3, b3,
                                                      cluster3, (unsigned*)xm4, N3c);
    segmax_decode<<<(512 * 128) / 256, 256, 0, stream>>>((unsigned*)xm4, 512 * 128);

    // FC head
    fc_fused<<<64, 256, 0, stream>>>(xm4, fc1_w, fc1_b, fc2_w, fc2_b, out);
}